// Round 1
// baseline (331.871 us; speedup 1.0000x reference)
//
#include <hip/hip_runtime.h>
#include <math.h>

#define BB 2
#define TT 8
#define NN 512
#define HH 64
#define NC 10
#define NEGV (-1e9f)

__device__ __forceinline__ float leaky02(float v){ return v >= 0.f ? v : 0.2f*v; }
__device__ __forceinline__ float elu1(float v){ return v > 0.f ? v : expm1f(v); }
__device__ __forceinline__ float sigm(float v){ return 1.f/(1.f+expf(-v)); }

// ---------------- K0: dyn = relu(W + W^T) ----------------
__global__ void k_dyn(const float* __restrict__ dW, float* __restrict__ dyn){
    int idx = blockIdx.x*256 + threadIdx.x;
    int i = idx / NN, j = idx % NN;
    float v = dW[i*NN+j] + dW[j*NN+i];
    dyn[idx] = v > 0.f ? v : 0.f;
}

// ---------------- K1: GAT layer 1 (Fin=1, heads=4, C=16), fused softmax+agg+elu
__global__ __launch_bounds__(256) void k_gat1(
    const float* __restrict__ x_seq, const float* __restrict__ sadj,
    const float* __restrict__ dyn, const float* __restrict__ lamp,
    const float* __restrict__ Wl, const float* __restrict__ Wr,
    const float* __restrict__ att, const float* __restrict__ bias,
    float* __restrict__ h1)
{
    __shared__ float Wl_s[64], Wr_s[64], att_s[64];
    __shared__ float e_s[NN][4];
    __shared__ float x_s[NN];
    __shared__ float S_s[4];
    int blk = blockIdx.x;
    int i = blk % NN; int bt = blk / NN; int t = bt % TT;
    int tid = threadIdx.x;
    if (tid < 64){ Wl_s[tid]=Wl[tid]; Wr_s[tid]=Wr[tid]; att_s[tid]=att[tid]; }
    __syncthreads();
    float lam = fmaxf(lamp[0], 0.01f);
    float g = expf(-lam * (float)t);
    float xi = x_seq[bt*NN + i];
    #pragma unroll
    for (int jj = 0; jj < 2; ++jj){
        int j = tid + jj*256;
        float xj = x_seq[bt*NN + j];
        x_s[j] = xj;
        float fused = g * sadj[i*NN+j] + (1.f-g)*dyn[i*NN+j];
        bool m = (fused > 0.f) || (i == j);
        #pragma unroll
        for (int h = 0; h < 4; ++h){
            float e = 0.f;
            #pragma unroll
            for (int c = 0; c < 16; ++c){
                int hc = h*16+c;
                e += att_s[hc] * leaky02(xi*Wr_s[hc] + xj*Wl_s[hc]);
            }
            e_s[j][h] = m ? e : NEGV;
        }
    }
    __syncthreads();
    int wave = tid >> 6, lane = tid & 63;
    if (wave < 4){
        int h = wave;
        float mx = -INFINITY;
        for (int j = lane; j < NN; j += 64) mx = fmaxf(mx, e_s[j][h]);
        for (int off=32; off; off>>=1) mx = fmaxf(mx, __shfl_down(mx, off));
        mx = __shfl(mx, 0);
        float se = 0.f, sx = 0.f;
        for (int j = lane; j < NN; j += 64){
            float w = expf(e_s[j][h]-mx);
            se += w; sx += w * x_s[j];
        }
        for (int off=32; off; off>>=1){ se += __shfl_down(se,off); sx += __shfl_down(sx,off); }
        if (lane == 0) S_s[h] = sx / se;
    }
    __syncthreads();
    if (tid < 64){
        float v = S_s[tid>>4] * Wl_s[tid] + bias[tid];
        h1[blk*64 + tid] = elu1(v);
    }
}

// ---------------- K2: xl2 = h1@Wl2, xr2 = h1@Wr2 (rows=B*T*N, 64x64) ----------
__global__ __launch_bounds__(256) void k_lin2(
    const float* __restrict__ h1, const float* __restrict__ Wl,
    const float* __restrict__ Wr, float* __restrict__ xl2, float* __restrict__ xr2)
{
    __shared__ float Wl_s[64*64];
    __shared__ float Wr_s[64*64];
    __shared__ float row_s[4][64];
    int tid = threadIdx.x;
    for (int k = tid; k < 4096; k += 256){ Wl_s[k]=Wl[k]; Wr_s[k]=Wr[k]; }
    int r = tid >> 6, c = tid & 63;
    int row0 = blockIdx.x * 4;
    row_s[r][c] = h1[(row0+r)*64 + c];
    __syncthreads();
    float al = 0.f, ar = 0.f;
    #pragma unroll
    for (int k = 0; k < 64; ++k){
        float a = row_s[r][k];
        al += a * Wl_s[k*64+c];
        ar += a * Wr_s[k*64+c];
    }
    xl2[(row0+r)*64+c] = al;
    xr2[(row0+r)*64+c] = ar;
}

// ---------------- K3: GAT layer 2 (heads=1, C=64) fused ------------------------
__global__ __launch_bounds__(256) void k_gat2(
    const float* __restrict__ xl2, const float* __restrict__ xr2,
    const float* __restrict__ sadj, const float* __restrict__ dyn,
    const float* __restrict__ lamp, const float* __restrict__ att,
    const float* __restrict__ bias, float* __restrict__ h2)
{
    __shared__ float att_s[64], xr_s[64];
    __shared__ float w_s[NN];
    __shared__ float red_s[256];
    __shared__ float part_s[4][64];
    __shared__ float bc_s[2];
    int blk = blockIdx.x;
    int i = blk % NN; int bt = blk / NN; int t = bt % TT;
    int tid = threadIdx.x;
    int base = bt * NN;
    if (tid < 64){ att_s[tid] = att[tid]; xr_s[tid] = xr2[(base+i)*64 + tid]; }
    __syncthreads();
    float lam = fmaxf(lamp[0], 0.01f);
    float g = expf(-lam*(float)t);
    float eloc[2];
    #pragma unroll
    for (int jj = 0; jj < 2; ++jj){
        int j = tid + jj*256;
        float fused = g*sadj[i*NN+j] + (1.f-g)*dyn[i*NN+j];
        bool m = (fused>0.f) || (i==j);
        float e = NEGV;
        if (m){
            e = 0.f;
            const float* xlrow = xl2 + (base+j)*64;
            #pragma unroll
            for (int c = 0; c < 64; ++c)
                e += att_s[c] * leaky02(xr_s[c] + xlrow[c]);
        }
        eloc[jj] = e;
    }
    // block max
    red_s[tid] = fmaxf(eloc[0], eloc[1]);
    __syncthreads();
    for (int s = 128; s; s >>= 1){ if (tid < s) red_s[tid] = fmaxf(red_s[tid], red_s[tid+s]); __syncthreads(); }
    if (tid == 0) bc_s[0] = red_s[0];
    __syncthreads();
    float mx = bc_s[0];
    float w0 = expf(eloc[0]-mx), w1 = expf(eloc[1]-mx);
    w_s[tid] = w0; w_s[tid+256] = w1;
    red_s[tid] = w0 + w1;
    __syncthreads();
    for (int s = 128; s; s >>= 1){ if (tid < s) red_s[tid] += red_s[tid+s]; __syncthreads(); }
    if (tid == 0) bc_s[1] = red_s[0];
    __syncthreads();
    float Z = bc_s[1];
    // aggregation: out[c] = (sum_j w_j * xl2[j,c]) / Z
    int c = tid & 63, q = tid >> 6;
    float acc = 0.f;
    for (int j = q*128; j < (q+1)*128; ++j)
        acc += w_s[j] * xl2[(base+j)*64 + c];
    part_s[q][c] = acc;
    __syncthreads();
    if (tid < 64){
        float s = (part_s[0][tid]+part_s[1][tid]+part_s[2][tid]+part_s[3][tid]) / Z;
        h2[(base+i)*64+tid] = elu1(s + bias[tid]);
    }
}

// ---------------- K4: node-mean readout -> hseq (B,T,H) ------------------------
__global__ __launch_bounds__(256) void k_mean(const float* __restrict__ h2, float* __restrict__ hseq){
    __shared__ float part_s[4][64];
    int bt = blockIdx.x; int tid = threadIdx.x;
    int c = tid & 63, q = tid >> 6;
    float acc = 0.f;
    for (int i = q*128; i < (q+1)*128; ++i) acc += h2[(bt*NN+i)*64 + c];
    part_s[q][c] = acc;
    __syncthreads();
    if (tid < 64) hseq[bt*64+tid] = (part_s[0][tid]+part_s[1][tid]+part_s[2][tid]+part_s[3][tid]) * (1.f/NN);
}

// ---------------- K5: one GRU layer, single block scan -------------------------
__global__ __launch_bounds__(384) void k_gru(
    const float* __restrict__ xin, const float* __restrict__ Wih,
    const float* __restrict__ Whh, const float* __restrict__ bih,
    const float* __restrict__ bhh, float* __restrict__ yout)
{
    __shared__ float h_s[BB][HH];
    __shared__ float gi_s[BB][192];
    __shared__ float gh_s[BB][192];
    int tid = threadIdx.x;
    int b = tid / 192, gidx = tid % 192;
    if (tid < BB*HH) h_s[tid>>6][tid&63] = 0.f;
    __syncthreads();
    for (int t = 0; t < TT; ++t){
        {
            const float* x = xin + (b*TT + t)*HH;
            float gi = bih[gidx], gh = bhh[gidx];
            for (int k = 0; k < HH; ++k){
                gi += x[k] * Wih[k*192 + gidx];
                gh += h_s[b][k] * Whh[k*192 + gidx];
            }
            gi_s[b][gidx] = gi; gh_s[b][gidx] = gh;
        }
        __syncthreads();
        if (tid < BB*HH){
            int bb2 = tid >> 6, gg = tid & 63;
            float r = sigm(gi_s[bb2][gg]      + gh_s[bb2][gg]);
            float z = sigm(gi_s[bb2][64+gg]   + gh_s[bb2][64+gg]);
            float n = tanhf(gi_s[bb2][128+gg] + r*gh_s[bb2][128+gg]);
            float hn = (1.f - z)*n + z*h_s[bb2][gg];
            h_s[bb2][gg] = hn;
            yout[(bb2*TT + t)*HH + gg] = hn;
        }
        __syncthreads();
    }
}

// ---------------- K6: temporal attention + classifier head ---------------------
__global__ __launch_bounds__(128) void k_head(
    const float* __restrict__ gru2, const float* __restrict__ lamp,
    const float* __restrict__ attn_W, const float* __restrict__ attn_b,
    const float* __restrict__ W1, const float* __restrict__ b1,
    const float* __restrict__ ln_g, const float* __restrict__ ln_b,
    const float* __restrict__ W2, const float* __restrict__ b2,
    float* __restrict__ out)
{
    __shared__ float sc_s[BB][TT], att_s[BB][TT];
    __shared__ float fin_s[BB][HH], z_s[BB][HH], g_s[BB][HH];
    __shared__ float mu_s[BB], iv_s[BB];
    int tid = threadIdx.x;
    float lam = fmaxf(lamp[0], 0.01f);
    if (tid < TT) out[BB*NC + tid] = expf(-lam*(float)tid);           // gts at [20..28)
    if (tid < BB*TT){
        int b = tid >> 3, t = tid & 7;
        float s = attn_b[0];
        const float* r = gru2 + (b*TT+t)*HH;
        for (int h = 0; h < HH; ++h) s += r[h]*attn_W[h];
        sc_s[b][t] = s;
    }
    __syncthreads();
    if (tid < BB){
        float mx = -INFINITY;
        for (int t = 0; t < TT; ++t) mx = fmaxf(mx, sc_s[tid][t]);
        float se = 0.f;
        for (int t = 0; t < TT; ++t){ float w = expf(sc_s[tid][t]-mx); att_s[tid][t]=w; se += w; }
        for (int t = 0; t < TT; ++t){
            att_s[tid][t] /= se;
            out[BB*NC + TT + tid*TT + t] = att_s[tid][t];             // att_scores at [28..44)
        }
    }
    __syncthreads();
    {   int b = tid >> 6, h = tid & 63;
        float a = 0.f;
        for (int t = 0; t < TT; ++t) a += att_s[b][t]*gru2[(b*TT+t)*HH + h];
        fin_s[b][h] = a; }
    __syncthreads();
    {   int b = tid >> 6, h = tid & 63;
        float a = b1[h];
        for (int k = 0; k < HH; ++k) a += fin_s[b][k]*W1[k*HH+h];
        z_s[b][h] = a; }
    __syncthreads();
    if (tid < BB){
        float mu = 0.f;
        for (int h = 0; h < HH; ++h) mu += z_s[tid][h];
        mu *= (1.f/HH);
        float v = 0.f;
        for (int h = 0; h < HH; ++h){ float d = z_s[tid][h]-mu; v += d*d; }
        v *= (1.f/HH);
        mu_s[tid] = mu; iv_s[tid] = 1.f/sqrtf(v + 1e-5f);
    }
    __syncthreads();
    {   int b = tid >> 6, h = tid & 63;
        float zn = (z_s[b][h]-mu_s[b])*iv_s[b]*ln_g[h] + ln_b[h];
        g_s[b][h] = 0.5f*zn*(1.f + erff(zn*0.70710678118654752f)); }
    __syncthreads();
    if (tid < BB*NC){
        int b = tid / NC, c = tid % NC;
        float a = b2[c];
        for (int k = 0; k < HH; ++k) a += g_s[b][k]*W2[k*NC+c];
        out[b*NC + c] = a;                                            // logits at [0..20)
    }
}

extern "C" void kernel_launch(void* const* d_in, const int* in_sizes, int n_in,
                              void* d_out, int out_size, void* d_ws, size_t ws_size,
                              hipStream_t stream)
{
    const float* x_seq = (const float*)d_in[0];
    const float* sadj  = (const float*)d_in[1];
    const float* dynW  = (const float*)d_in[2];
    const float* lamp  = (const float*)d_in[3];
    const float* g1_Wl = (const float*)d_in[4];
    const float* g1_Wr = (const float*)d_in[5];
    const float* g1_att= (const float*)d_in[6];
    const float* g1_b  = (const float*)d_in[7];
    const float* g2_Wl = (const float*)d_in[8];
    const float* g2_Wr = (const float*)d_in[9];
    const float* g2_att= (const float*)d_in[10];
    const float* g2_b  = (const float*)d_in[11];
    const float* Wih0  = (const float*)d_in[12];
    const float* Whh0  = (const float*)d_in[13];
    const float* bih0  = (const float*)d_in[14];
    const float* bhh0  = (const float*)d_in[15];
    const float* Wih1  = (const float*)d_in[16];
    const float* Whh1  = (const float*)d_in[17];
    const float* bih1  = (const float*)d_in[18];
    const float* bhh1  = (const float*)d_in[19];
    const float* attnW = (const float*)d_in[20];
    const float* attnb = (const float*)d_in[21];
    const float* W1    = (const float*)d_in[22];
    const float* b1    = (const float*)d_in[23];
    const float* lng   = (const float*)d_in[24];
    const float* lnb   = (const float*)d_in[25];
    const float* W2    = (const float*)d_in[26];
    const float* b2    = (const float*)d_in[27];
    float* out = (float*)d_out;
    float* ws  = (float*)d_ws;

    const int RWS = BB*TT*NN*HH;    // 524288 rows*H
    float* dyn  = ws;               // N*N
    float* h1   = dyn  + NN*NN;     // RWS  (consumed by k_lin2; reused as h2)
    float* xl2  = h1   + RWS;       // RWS
    float* xr2  = xl2  + RWS;       // RWS
    float* h2   = h1;               // alias: h1 dead after k_lin2
    float* hseq = xr2  + RWS;       // B*T*H
    float* gru1 = hseq + BB*TT*HH;  // B*T*H
    float* gru2 = gru1 + BB*TT*HH;  // B*T*H
    // total ws: ~7.1 MB

    k_dyn <<<NN*NN/256, 256, 0, stream>>>(dynW, dyn);
    k_gat1<<<BB*TT*NN, 256, 0, stream>>>(x_seq, sadj, dyn, lamp, g1_Wl, g1_Wr, g1_att, g1_b, h1);
    k_lin2<<<BB*TT*NN/4, 256, 0, stream>>>(h1, g2_Wl, g2_Wr, xl2, xr2);
    k_gat2<<<BB*TT*NN, 256, 0, stream>>>(xl2, xr2, sadj, dyn, lamp, g2_att, g2_b, h2);
    k_mean<<<BB*TT, 256, 0, stream>>>(h2, hseq);
    k_gru <<<1, 384, 0, stream>>>(hseq, Wih0, Whh0, bih0, bhh0, gru1);
    k_gru <<<1, 384, 0, stream>>>(gru1, Wih1, Whh1, bih1, bhh1, gru2);
    k_head<<<1, 128, 0, stream>>>(gru2, lamp, attnW, attnb, W1, b1, lng, lnb, W2, b2, out);
}

// Round 2
// 318.382 us; speedup vs baseline: 1.0424x; 1.0424x over previous
//
#include <hip/hip_runtime.h>
#include <math.h>

#define BB 2
#define TT 8
#define NN 512
#define HH 64
#define NC 10

__device__ __forceinline__ float leaky02(float v){ return fmaxf(v, 0.2f*v); }
__device__ __forceinline__ float elu1(float v){ return v > 0.f ? v : expm1f(v); }
__device__ __forceinline__ float sigm(float v){ return 1.f/(1.f+expf(-v)); }

// ---------------- K0: dyn = relu(W + W^T); also zero Z2 ----------------
__global__ void k_dyn(const float* __restrict__ dW, float* __restrict__ dyn,
                      float* __restrict__ Z2){
    int idx = blockIdx.x*256 + threadIdx.x;
    int i = idx / NN, j = idx % NN;
    float v = dW[i*NN+j] + dW[j*NN+i];
    dyn[idx] = v > 0.f ? v : 0.f;
    if (idx < BB*TT*NN) Z2[idx] = 0.f;
}

// ---------------- K1: GAT layer 1 fused (Fin=1, heads=4, C=16) ----------------
// block: 4 i-rows x 64 j-lanes. grid: (NN/4, B*T)
__global__ __launch_bounds__(256) void k_gat1(
    const float* __restrict__ x_seq, const float* __restrict__ sadj,
    const float* __restrict__ dyn, const float* __restrict__ lamp,
    const float* __restrict__ Wl, const float* __restrict__ Wr,
    const float* __restrict__ att, const float* __restrict__ bias,
    float* __restrict__ h1)
{
    __shared__ float x_s[NN];
    __shared__ float S_s[4][4];     // [il][h] = Sx/Sw
    int bt = blockIdx.y; int t = bt % TT;
    int i0 = blockIdx.x * 4;
    int tid = threadIdx.x;
    int il = tid >> 6, jl = tid & 63;
    int i = i0 + il;
    // stage x row (512 floats) via float2
    ((float2*)x_s)[tid] = ((const float2*)(x_seq + bt*NN))[tid];
    __syncthreads();
    float lam = fmaxf(lamp[0], 0.01f);
    float g = expf(-lam * (float)t);
    float xi = x_s[i];
    float sw[4] = {0,0,0,0}, swx[4] = {0,0,0,0};
    for (int jc = 0; jc < 8; ++jc){
        int j = jc*64 + jl;
        float xj = x_s[j];
        float fused = g*sadj[i*NN+j] + (1.f-g)*dyn[i*NN+j];
        bool m = (fused > 0.f) || (i == j);
        #pragma unroll
        for (int h = 0; h < 4; ++h){
            float e = 0.f;
            #pragma unroll
            for (int c = 0; c < 16; ++c){
                int hc = h*16+c;                    // uniform index -> s_load
                float s = fmaf(xi, Wr[hc], xj*Wl[hc]);
                e = fmaf(att[hc], leaky02(s), e);
            }
            float w = m ? expf(e) : 0.f;
            sw[h] += w; swx[h] += w*xj;
        }
    }
    // wave reduce over 64 jl lanes (wave == il)
    #pragma unroll
    for (int off = 32; off; off >>= 1){
        #pragma unroll
        for (int h = 0; h < 4; ++h){
            sw[h]  += __shfl_down(sw[h],  off);
            swx[h] += __shfl_down(swx[h], off);
        }
    }
    if (jl == 0){
        #pragma unroll
        for (int h = 0; h < 4; ++h) S_s[il][h] = swx[h] / sw[h];
    }
    __syncthreads();
    {   // 256 threads: (il, hc) -> h1
        int hc = tid & 63, ilo = tid >> 6;
        float v = S_s[ilo][hc >> 4] * Wl[hc] + bias[hc];
        h1[(bt*NN + i0 + ilo)*HH + hc] = elu1(v);
    }
}

// ---------------- K2: xl2 = h1@Wl2, xr2 = h1@Wr2 ----------------
__global__ __launch_bounds__(256) void k_lin2(
    const float* __restrict__ h1, const float* __restrict__ Wl,
    const float* __restrict__ Wr, float* __restrict__ xl2, float* __restrict__ xr2)
{
    __shared__ float Wl_s[64*64];
    __shared__ float Wr_s[64*64];
    __shared__ float row_s[4][64];
    int tid = threadIdx.x;
    for (int k = tid; k < 4096; k += 256){ Wl_s[k]=Wl[k]; Wr_s[k]=Wr[k]; }
    int r = tid >> 6, c = tid & 63;
    int row0 = blockIdx.x * 4;
    row_s[r][c] = h1[(row0+r)*64 + c];
    __syncthreads();
    float al = 0.f, ar = 0.f;
    #pragma unroll
    for (int k = 0; k < 64; ++k){
        float a = row_s[r][k];
        al += a * Wl_s[k*64+c];
        ar += a * Wr_s[k*64+c];
    }
    xl2[(row0+r)*64+c] = al;
    xr2[(row0+r)*64+c] = ar;
}

// ---------------- K3a: GAT2 e-scores -> W = exp(e) (masked->0), Z via atomics --
// block: 16i x 16j tile. grid: (NN/16, NN/16, B*T)
#define PIT 68
__global__ __launch_bounds__(256) void k_e2(
    const float* __restrict__ xl2, const float* __restrict__ xr2,
    const float* __restrict__ sadj, const float* __restrict__ dyn,
    const float* __restrict__ lamp, const float* __restrict__ att,
    float* __restrict__ Wg, float* __restrict__ Z2)
{
    __shared__ float xr_s[16][PIT];
    __shared__ float xl_s[16][PIT];
    int bt = blockIdx.z; int t = bt % TT;
    int i0 = blockIdx.y * 16, j0 = blockIdx.x * 16;
    int base = bt * NN;
    int tid = threadIdx.x;
    // stage 16x64 tiles as float4: tid -> (row=tid/16, c4=tid%16)
    {
        int row = tid >> 4, c4 = tid & 15;
        float4 a = ((const float4*)(xr2 + (base+i0+row)*HH))[c4];
        float4 b = ((const float4*)(xl2 + (base+j0+row)*HH))[c4];
        ((float4*)&xr_s[row][0])[c4] = a;
        ((float4*)&xl_s[row][0])[c4] = b;
    }
    int il = tid >> 4, jl = tid & 15;
    int i = i0 + il, j = j0 + jl;
    float lam = fmaxf(lamp[0], 0.01f);
    float g = expf(-lam*(float)t);
    float fused = g*sadj[i*NN+j] + (1.f-g)*dyn[i*NN+j];
    bool m = (fused > 0.f) || (i == j);
    __syncthreads();
    const float4* xrv = (const float4*)&xr_s[il][0];
    const float4* xlv = (const float4*)&xl_s[jl][0];
    const float4* attv = (const float4*)att;
    float e = 0.f;
    #pragma unroll
    for (int c4 = 0; c4 < 16; ++c4){
        float4 a = xrv[c4], b = xlv[c4], t4 = attv[c4];  // att: uniform -> s_load
        float s0 = a.x+b.x, s1 = a.y+b.y, s2 = a.z+b.z, s3 = a.w+b.w;
        e = fmaf(t4.x, leaky02(s0), e);
        e = fmaf(t4.y, leaky02(s1), e);
        e = fmaf(t4.z, leaky02(s2), e);
        e = fmaf(t4.w, leaky02(s3), e);
    }
    float w = m ? expf(e) : 0.f;
    Wg[(base + i)*NN + j] = w;
    // reduce w over 16 j-lanes, one atomic per (block, i-row)
    float zs = w;
    zs += __shfl_down(zs, 8);
    zs += __shfl_down(zs, 4);
    zs += __shfl_down(zs, 2);
    zs += __shfl_down(zs, 1);
    if (jl == 0) atomicAdd(&Z2[base + i], zs);
}

// ---------------- K3b: h2 = elu( (W @ xl2)/Z + bias ) --------------------------
// block: 64i x 64c tile, 4x4 micro-tile. grid: (NN/64, B*T)
__global__ __launch_bounds__(256) void k_a2(
    const float* __restrict__ Wg, const float* __restrict__ xl2,
    const float* __restrict__ Z2, const float* __restrict__ bias,
    float* __restrict__ h2)
{
    __shared__ float W_s[64][PIT];
    __shared__ float xl_s[64][PIT];
    int bt = blockIdx.y;
    int i0 = blockIdx.x * 64;
    int base = bt * NN;
    int tid = threadIdx.x;
    int ti = tid >> 4, tc = tid & 15;     // 16 i-groups x 16 c4
    int im = ti * 4;                       // 4 i rows per thread
    float4 acc[4] = {{0,0,0,0},{0,0,0,0},{0,0,0,0},{0,0,0,0}};
    for (int jc = 0; jc < 8; ++jc){
        int j0 = jc * 64;
        // stage W 64x64 chunk and xl 64x64 chunk
        for (int v = tid; v < 64*16; v += 256){
            int row = v >> 4, c4 = v & 15;
            ((float4*)&W_s[row][0])[c4]  = ((const float4*)(Wg  + (base+i0+row)*NN + j0))[c4];
            ((float4*)&xl_s[row][0])[c4] = ((const float4*)(xl2 + (base+j0+row)*HH))[c4];
        }
        __syncthreads();
        const float4* w0 = (const float4*)&W_s[im+0][0];
        const float4* w1 = (const float4*)&W_s[im+1][0];
        const float4* w2 = (const float4*)&W_s[im+2][0];
        const float4* w3 = (const float4*)&W_s[im+3][0];
        #pragma unroll
        for (int jq = 0; jq < 16; ++jq){
            float4 x0 = ((const float4*)&xl_s[jq*4+0][0])[tc];
            float4 x1 = ((const float4*)&xl_s[jq*4+1][0])[tc];
            float4 x2 = ((const float4*)&xl_s[jq*4+2][0])[tc];
            float4 x3 = ((const float4*)&xl_s[jq*4+3][0])[tc];
            float4 a0 = w0[jq], a1 = w1[jq], a2 = w2[jq], a3 = w3[jq];
            acc[0].x += a0.x*x0.x + a0.y*x1.x + a0.z*x2.x + a0.w*x3.x;
            acc[0].y += a0.x*x0.y + a0.y*x1.y + a0.z*x2.y + a0.w*x3.y;
            acc[0].z += a0.x*x0.z + a0.y*x1.z + a0.z*x2.z + a0.w*x3.z;
            acc[0].w += a0.x*x0.w + a0.y*x1.w + a0.z*x2.w + a0.w*x3.w;
            acc[1].x += a1.x*x0.x + a1.y*x1.x + a1.z*x2.x + a1.w*x3.x;
            acc[1].y += a1.x*x0.y + a1.y*x1.y + a1.z*x2.y + a1.w*x3.y;
            acc[1].z += a1.x*x0.z + a1.y*x1.z + a1.z*x2.z + a1.w*x3.z;
            acc[1].w += a1.x*x0.w + a1.y*x1.w + a1.z*x2.w + a1.w*x3.w;
            acc[2].x += a2.x*x0.x + a2.y*x1.x + a2.z*x2.x + a2.w*x3.x;
            acc[2].y += a2.x*x0.y + a2.y*x1.y + a2.z*x2.y + a2.w*x3.y;
            acc[2].z += a2.x*x0.z + a2.y*x1.z + a2.z*x2.z + a2.w*x3.z;
            acc[2].w += a2.x*x0.w + a2.y*x1.w + a2.z*x2.w + a2.w*x3.w;
            acc[3].x += a3.x*x0.x + a3.y*x1.x + a3.z*x2.x + a3.w*x3.x;
            acc[3].y += a3.x*x0.y + a3.y*x1.y + a3.z*x2.y + a3.w*x3.y;
            acc[3].z += a3.x*x0.z + a3.y*x1.z + a3.z*x2.z + a3.w*x3.z;
            acc[3].w += a3.x*x0.w + a3.y*x1.w + a3.z*x2.w + a3.w*x3.w;
        }
        __syncthreads();
    }
    float4 bia = ((const float4*)bias)[tc];
    #pragma unroll
    for (int ii = 0; ii < 4; ++ii){
        float rinv = 1.f / Z2[base + i0 + im + ii];
        float4 o;
        o.x = elu1(acc[ii].x*rinv + bia.x);
        o.y = elu1(acc[ii].y*rinv + bia.y);
        o.z = elu1(acc[ii].z*rinv + bia.z);
        o.w = elu1(acc[ii].w*rinv + bia.w);
        ((float4*)(h2 + (base + i0 + im + ii)*HH))[tc] = o;
    }
}

// ---------------- K4: node-mean readout -> hseq (B,T,H) ------------------------
__global__ __launch_bounds__(256) void k_mean(const float* __restrict__ h2, float* __restrict__ hseq){
    __shared__ float part_s[4][64];
    int bt = blockIdx.x; int tid = threadIdx.x;
    int c = tid & 63, q = tid >> 6;
    float acc = 0.f;
    for (int i = q*128; i < (q+1)*128; ++i) acc += h2[(bt*NN+i)*64 + c];
    part_s[q][c] = acc;
    __syncthreads();
    if (tid < 64) hseq[bt*64+tid] = (part_s[0][tid]+part_s[1][tid]+part_s[2][tid]+part_s[3][tid]) * (1.f/NN);
}

// ---------------- K5: one GRU layer, single block; Whh in LDS, gi precomputed --
__global__ __launch_bounds__(384) void k_gru(
    const float* __restrict__ xin, const float* __restrict__ Wih,
    const float* __restrict__ Whh, const float* __restrict__ bih,
    const float* __restrict__ bhh, float* __restrict__ yout)
{
    __shared__ float Whh_s[64*192];      // 48 KB
    __shared__ float gi_s[BB*TT*192];    // 12 KB
    __shared__ float h_s[BB][HH];
    __shared__ float gh_s[BB][192];
    int tid = threadIdx.x;
    for (int k = tid; k < 64*192; k += 384) Whh_s[k] = Whh[k];
    // precompute input gates for all (b,t)
    for (int o = tid; o < BB*TT*192; o += 384){
        int bt = o / 192, g = o % 192;
        const float* x = xin + bt*HH;
        float acc = bih[g];
        for (int k = 0; k < HH; ++k) acc += x[k]*Wih[k*192+g];
        gi_s[o] = acc;
    }
    if (tid < BB*HH) h_s[tid>>6][tid&63] = 0.f;
    __syncthreads();
    int b = tid / 192, g = tid % 192;
    for (int t = 0; t < TT; ++t){
        float gh = bhh[g];
        #pragma unroll 8
        for (int k = 0; k < HH; ++k) gh += h_s[b][k]*Whh_s[k*192+g];
        gh_s[b][g] = gh;
        __syncthreads();
        if (tid < BB*HH){
            int b2 = tid >> 6, gg = tid & 63;
            const float* gi = &gi_s[(b2*TT+t)*192];
            float r = sigm(gi[gg]      + gh_s[b2][gg]);
            float z = sigm(gi[64+gg]   + gh_s[b2][64+gg]);
            float n = tanhf(gi[128+gg] + r*gh_s[b2][128+gg]);
            float hn = (1.f - z)*n + z*h_s[b2][gg];
            h_s[b2][gg] = hn;
            yout[(b2*TT + t)*HH + gg] = hn;
        }
        __syncthreads();
    }
}

// ---------------- K6: temporal attention + classifier head ---------------------
__global__ __launch_bounds__(128) void k_head(
    const float* __restrict__ gru2, const float* __restrict__ lamp,
    const float* __restrict__ attn_W, const float* __restrict__ attn_b,
    const float* __restrict__ W1, const float* __restrict__ b1,
    const float* __restrict__ ln_g, const float* __restrict__ ln_b,
    const float* __restrict__ W2, const float* __restrict__ b2,
    float* __restrict__ out)
{
    __shared__ float sc_s[BB][TT], att_s[BB][TT];
    __shared__ float fin_s[BB][HH], z_s[BB][HH], g_s[BB][HH];
    __shared__ float mu_s[BB], iv_s[BB];
    int tid = threadIdx.x;
    float lam = fmaxf(lamp[0], 0.01f);
    if (tid < TT) out[BB*NC + tid] = expf(-lam*(float)tid);           // gts at [20..28)
    if (tid < BB*TT){
        int b = tid >> 3, t = tid & 7;
        float s = attn_b[0];
        const float* r = gru2 + (b*TT+t)*HH;
        for (int h = 0; h < HH; ++h) s += r[h]*attn_W[h];
        sc_s[b][t] = s;
    }
    __syncthreads();
    if (tid < BB){
        float mx = -INFINITY;
        for (int t = 0; t < TT; ++t) mx = fmaxf(mx, sc_s[tid][t]);
        float se = 0.f;
        for (int t = 0; t < TT; ++t){ float w = expf(sc_s[tid][t]-mx); att_s[tid][t]=w; se += w; }
        for (int t = 0; t < TT; ++t){
            att_s[tid][t] /= se;
            out[BB*NC + TT + tid*TT + t] = att_s[tid][t];             // att_scores at [28..44)
        }
    }
    __syncthreads();
    {   int b = tid >> 6, h = tid & 63;
        float a = 0.f;
        for (int t = 0; t < TT; ++t) a += att_s[b][t]*gru2[(b*TT+t)*HH + h];
        fin_s[b][h] = a; }
    __syncthreads();
    {   int b = tid >> 6, h = tid & 63;
        float a = b1[h];
        for (int k = 0; k < HH; ++k) a += fin_s[b][k]*W1[k*HH+h];
        z_s[b][h] = a; }
    __syncthreads();
    if (tid < BB){
        float mu = 0.f;
        for (int h = 0; h < HH; ++h) mu += z_s[tid][h];
        mu *= (1.f/HH);
        float v = 0.f;
        for (int h = 0; h < HH; ++h){ float d = z_s[tid][h]-mu; v += d*d; }
        v *= (1.f/HH);
        mu_s[tid] = mu; iv_s[tid] = 1.f/sqrtf(v + 1e-5f);
    }
    __syncthreads();
    {   int b = tid >> 6, h = tid & 63;
        float zn = (z_s[b][h]-mu_s[b])*iv_s[b]*ln_g[h] + ln_b[h];
        g_s[b][h] = 0.5f*zn*(1.f + erff(zn*0.70710678118654752f)); }
    __syncthreads();
    if (tid < BB*NC){
        int b = tid / NC, c = tid % NC;
        float a = b2[c];
        for (int k = 0; k < HH; ++k) a += g_s[b][k]*W2[k*NC+c];
        out[b*NC + c] = a;                                            // logits at [0..20)
    }
}

extern "C" void kernel_launch(void* const* d_in, const int* in_sizes, int n_in,
                              void* d_out, int out_size, void* d_ws, size_t ws_size,
                              hipStream_t stream)
{
    const float* x_seq = (const float*)d_in[0];
    const float* sadj  = (const float*)d_in[1];
    const float* dynW  = (const float*)d_in[2];
    const float* lamp  = (const float*)d_in[3];
    const float* g1_Wl = (const float*)d_in[4];
    const float* g1_Wr = (const float*)d_in[5];
    const float* g1_att= (const float*)d_in[6];
    const float* g1_b  = (const float*)d_in[7];
    const float* g2_Wl = (const float*)d_in[8];
    const float* g2_Wr = (const float*)d_in[9];
    const float* g2_att= (const float*)d_in[10];
    const float* g2_b  = (const float*)d_in[11];
    const float* Wih0  = (const float*)d_in[12];
    const float* Whh0  = (const float*)d_in[13];
    const float* bih0  = (const float*)d_in[14];
    const float* bhh0  = (const float*)d_in[15];
    const float* Wih1  = (const float*)d_in[16];
    const float* Whh1  = (const float*)d_in[17];
    const float* bih1  = (const float*)d_in[18];
    const float* bhh1  = (const float*)d_in[19];
    const float* attnW = (const float*)d_in[20];
    const float* attnb = (const float*)d_in[21];
    const float* W1    = (const float*)d_in[22];
    const float* b1    = (const float*)d_in[23];
    const float* lng   = (const float*)d_in[24];
    const float* lnb   = (const float*)d_in[25];
    const float* W2    = (const float*)d_in[26];
    const float* b2    = (const float*)d_in[27];
    float* out = (float*)d_out;
    float* ws  = (float*)d_ws;

    const int RWS = BB*TT*NN*HH;         // 524288
    float* dyn  = ws;                    // 262144
    float* Z2   = dyn  + NN*NN;          // 8192
    float* h1   = Z2   + BB*TT*NN;       // RWS (reused as h2)
    float* xl2  = h1   + RWS;            // RWS
    float* xr2  = xl2  + RWS;            // RWS
    float* Wbuf = xr2  + RWS;            // 16*512*512 = 4194304
    float* h2   = h1;                    // alias: h1 dead after k_lin2
    float* hseq = Wbuf + BB*TT*NN*NN;    // 1024
    float* gru1 = hseq + BB*TT*HH;       // 1024
    float* gru2 = gru1 + BB*TT*HH;       // 1024
    // total ws: ~24.2 MB

    k_dyn <<<NN*NN/256, 256, 0, stream>>>(dynW, dyn, Z2);
    k_gat1<<<dim3(NN/4, BB*TT), 256, 0, stream>>>(x_seq, sadj, dyn, lamp, g1_Wl, g1_Wr, g1_att, g1_b, h1);
    k_lin2<<<BB*TT*NN/4, 256, 0, stream>>>(h1, g2_Wl, g2_Wr, xl2, xr2);
    k_e2  <<<dim3(NN/16, NN/16, BB*TT), 256, 0, stream>>>(xl2, xr2, sadj, dyn, lamp, g2_att, Wbuf, Z2);
    k_a2  <<<dim3(NN/64, BB*TT), 256, 0, stream>>>(Wbuf, xl2, Z2, g2_b, h2);
    k_mean<<<BB*TT, 256, 0, stream>>>(h2, hseq);
    k_gru <<<1, 384, 0, stream>>>(hseq, Wih0, Whh0, bih0, bhh0, gru1);
    k_gru <<<1, 384, 0, stream>>>(gru1, Wih1, Whh1, bih1, bhh1, gru2);
    k_head<<<1, 128, 0, stream>>>(gru2, lamp, attnW, attnb, W1, b1, lng, lnb, W2, b2, out);
}

// Round 3
// 228.019 us; speedup vs baseline: 1.4555x; 1.3963x over previous
//
#include <hip/hip_runtime.h>
#include <math.h>

#define BB 2
#define TT 8
#define NN 512
#define HH 64
#define NC 10

__device__ __forceinline__ float elu1(float v){ return v > 0.f ? v : expm1f(v); }
__device__ __forceinline__ float sigm(float v){ return 1.f/(1.f+expf(-v)); }

// ---------------- K0: dyn = relu(W+W^T); zero Z2/hseq; compute Ar/Al ----------
__global__ void k_dyn(const float* __restrict__ dW, float* __restrict__ dyn,
                      float* __restrict__ Z2, float* __restrict__ hseq,
                      const float* __restrict__ att1, const float* __restrict__ Wr1,
                      const float* __restrict__ Wl1, float* __restrict__ AB){
    int idx = blockIdx.x*256 + threadIdx.x;
    int i = idx / NN, j = idx % NN;
    float v = dW[i*NN+j] + dW[j*NN+i];
    dyn[idx] = v > 0.f ? v : 0.f;
    if (idx < BB*TT*NN) Z2[idx] = 0.f;
    if (idx >= 262000 && idx < 262000 + BB*TT*HH) hseq[idx-262000] = 0.f;
    if (blockIdx.x == 0 && threadIdx.x < 8){
        int h = threadIdx.x & 3;
        const float* W = (threadIdx.x < 4) ? Wr1 : Wl1;
        float s = 0.f;
        for (int c = 0; c < 16; ++c) s += att1[h*16+c]*W[h*16+c];
        AB[threadIdx.x] = s;   // [0..4)=Ar_h, [4..8)=Al_h
    }
}

// ---------------- K1: GAT layer 1 fused (Fin=1, heads=4, C=16) ----------------
// e^h = 0.6(xi*Ar_h + xj*Al_h) + sum_c 0.4*att|xi*Wr + xj*Wl|
// block: 4 i-rows x 64 j-lanes (8 j each). grid: (NN/4, B*T)
__global__ __launch_bounds__(256) void k_gat1(
    const float* __restrict__ x_seq, const float* __restrict__ sadj,
    const float* __restrict__ dyn, const float* __restrict__ lamp,
    const float* __restrict__ Wl, const float* __restrict__ Wr,
    const float* __restrict__ att, const float* __restrict__ bias,
    const float* __restrict__ AB, float* __restrict__ h1)
{
    __shared__ float x_s[NN];
    __shared__ float S_s[4][4];
    int bt = blockIdx.y; int t = bt % TT;
    int i0 = blockIdx.x * 4;
    int tid = threadIdx.x;
    int il = tid >> 6, jl = tid & 63;
    int i = i0 + il;
    ((float2*)x_s)[tid] = ((const float2*)(x_seq + bt*NN))[tid];
    __syncthreads();
    float lam = fmaxf(lamp[0], 0.01f);
    float g = expf(-lam * (float)t);
    float xi = x_s[i];
    float xj[8], msk[8];
    #pragma unroll
    for (int jj = 0; jj < 8; ++jj){
        int j = jj*64 + jl;
        xj[jj] = x_s[j];
        float fused = g*sadj[i*NN+j] + (1.f-g)*dyn[i*NN+j];
        msk[jj] = ((fused > 0.f) || (i == j)) ? 1.f : 0.f;
    }
    float sw[4] = {0,0,0,0}, swx[4] = {0,0,0,0};
    for (int h = 0; h < 4; ++h){
        float acc[8] = {0,0,0,0,0,0,0,0};
        #pragma unroll
        for (int c = 0; c < 16; ++c){
            int hc = h*16 + c;
            float wl = Wl[hc];
            float q  = 0.4f * att[hc];
            float pr = xi * Wr[hc];
            #pragma unroll
            for (int jj = 0; jj < 8; ++jj){
                float s = fmaf(xj[jj], wl, pr);
                acc[jj] = fmaf(q, fabsf(s), acc[jj]);
            }
        }
        float lin = 0.6f * xi * AB[h];
        float al6 = 0.6f * AB[4+h];
        #pragma unroll
        for (int jj = 0; jj < 8; ++jj){
            float e = acc[jj] + fmaf(al6, xj[jj], lin);
            float w = msk[jj] * expf(e);
            sw[h] += w;
            swx[h] = fmaf(w, xj[jj], swx[h]);
        }
    }
    #pragma unroll
    for (int off = 32; off; off >>= 1){
        #pragma unroll
        for (int h = 0; h < 4; ++h){
            sw[h]  += __shfl_down(sw[h],  off);
            swx[h] += __shfl_down(swx[h], off);
        }
    }
    if (jl == 0){
        #pragma unroll
        for (int h = 0; h < 4; ++h) S_s[il][h] = swx[h] / sw[h];
    }
    __syncthreads();
    {
        int hc = tid & 63, ilo = tid >> 6;
        float v = S_s[ilo][hc >> 4] * Wl[hc] + bias[hc];
        h1[(bt*NN + i0 + ilo)*HH + hc] = elu1(v);
    }
}

// ---------------- K2: xl2/xr2 = h1@{Wl2,Wr2} + ui/vj att-dots ------------------
// 32 rows/block, grid 256. thread = (tr16 x tc16): rows {tr, tr+16}, c-quad tc.
__global__ __launch_bounds__(256) void k_lin2(
    const float* __restrict__ h1, const float* __restrict__ Wl,
    const float* __restrict__ Wr, const float* __restrict__ att,
    float* __restrict__ xl2, float* __restrict__ xr2,
    float* __restrict__ ui, float* __restrict__ vj)
{
    __shared__ float Wl_s[64][68];
    __shared__ float Wr_s[64][68];
    __shared__ float row_s[32][68];
    int tid = threadIdx.x;
    #pragma unroll
    for (int q = 0; q < 4; ++q){
        int idx = q*256 + tid; int r = idx >> 4, c4 = idx & 15;
        ((float4*)&Wl_s[r][0])[c4] = ((const float4*)&Wl[r*64])[c4];
        ((float4*)&Wr_s[r][0])[c4] = ((const float4*)&Wr[r*64])[c4];
    }
    int row0 = blockIdx.x * 32;
    #pragma unroll
    for (int q = 0; q < 2; ++q){
        int idx = q*256 + tid; int r = idx >> 4, c4 = idx & 15;
        ((float4*)&row_s[r][0])[c4] = ((const float4*)&h1[(row0+r)*HH])[c4];
    }
    __syncthreads();
    int tr = tid >> 4, tc = tid & 15;
    float4 al0={0,0,0,0}, al1={0,0,0,0}, ar0={0,0,0,0}, ar1={0,0,0,0};
    #pragma unroll 4
    for (int k = 0; k < 64; ++k){
        float r0 = row_s[tr][k], r1 = row_s[tr+16][k];
        float4 wl4 = ((float4*)&Wl_s[k][0])[tc];
        float4 wr4 = ((float4*)&Wr_s[k][0])[tc];
        al0.x = fmaf(r0, wl4.x, al0.x); al0.y = fmaf(r0, wl4.y, al0.y);
        al0.z = fmaf(r0, wl4.z, al0.z); al0.w = fmaf(r0, wl4.w, al0.w);
        al1.x = fmaf(r1, wl4.x, al1.x); al1.y = fmaf(r1, wl4.y, al1.y);
        al1.z = fmaf(r1, wl4.z, al1.z); al1.w = fmaf(r1, wl4.w, al1.w);
        ar0.x = fmaf(r0, wr4.x, ar0.x); ar0.y = fmaf(r0, wr4.y, ar0.y);
        ar0.z = fmaf(r0, wr4.z, ar0.z); ar0.w = fmaf(r0, wr4.w, ar0.w);
        ar1.x = fmaf(r1, wr4.x, ar1.x); ar1.y = fmaf(r1, wr4.y, ar1.y);
        ar1.z = fmaf(r1, wr4.z, ar1.z); ar1.w = fmaf(r1, wr4.w, ar1.w);
    }
    ((float4*)&xl2[(size_t)(row0+tr)*HH])[tc]    = al0;
    ((float4*)&xl2[(size_t)(row0+tr+16)*HH])[tc] = al1;
    ((float4*)&xr2[(size_t)(row0+tr)*HH])[tc]    = ar0;
    ((float4*)&xr2[(size_t)(row0+tr+16)*HH])[tc] = ar1;
    float4 a4 = ((const float4*)att)[tc];
    float pu0 = a4.x*ar0.x + a4.y*ar0.y + a4.z*ar0.z + a4.w*ar0.w;
    float pu1 = a4.x*ar1.x + a4.y*ar1.y + a4.z*ar1.z + a4.w*ar1.w;
    float pv0 = a4.x*al0.x + a4.y*al0.y + a4.z*al0.z + a4.w*al0.w;
    float pv1 = a4.x*al1.x + a4.y*al1.y + a4.z*al1.z + a4.w*al1.w;
    #pragma unroll
    for (int off = 8; off; off >>= 1){
        pu0 += __shfl_down(pu0, off); pu1 += __shfl_down(pu1, off);
        pv0 += __shfl_down(pv0, off); pv1 += __shfl_down(pv1, off);
    }
    if (tc == 0){
        ui[row0+tr] = pu0; ui[row0+tr+16] = pu1;
        vj[row0+tr] = pv0; vj[row0+tr+16] = pv1;
    }
}

// ---------------- K3a: GAT2 scores -> WgT[j][i] = exp(e) (masked->0), Z atomics
// block tile 64i x 64j, thread = 4i x 4j. grid (8, 8, 16)
__global__ __launch_bounds__(256) void k_e2(
    const float* __restrict__ xl2, const float* __restrict__ xr2,
    const float* __restrict__ sadj, const float* __restrict__ dyn,
    const float* __restrict__ lamp, const float* __restrict__ att,
    const float* __restrict__ ui, const float* __restrict__ vj,
    float* __restrict__ WgT, float* __restrict__ Z2)
{
    __shared__ float xr_s[64][68];
    __shared__ float xl_s[64][68];
    int bt = blockIdx.z, t = bt % TT;
    int i0 = blockIdx.y*64, j0 = blockIdx.x*64;
    int base = bt*NN;
    int tid = threadIdx.x;
    {
        int r = tid >> 2;
        #pragma unroll
        for (int q = 0; q < 4; ++q){
            int c4 = (tid & 3) + q*4;
            ((float4*)&xr_s[r][0])[c4] = ((const float4*)&xr2[(size_t)(base+i0+r)*HH])[c4];
            ((float4*)&xl_s[r][0])[c4] = ((const float4*)&xl2[(size_t)(base+j0+r)*HH])[c4];
        }
    }
    int ti = tid >> 4, tj = tid & 15;
    int iL = ti*4, jL = tj*4;
    float lam = fmaxf(lamp[0], 0.01f);
    float g = expf(-lam*(float)t);
    float4 u4 = *(const float4*)&ui[base+i0+iL];
    float4 v4 = *(const float4*)&vj[base+j0+jL];
    float uu[4] = {u4.x, u4.y, u4.z, u4.w};
    float vv[4] = {v4.x, v4.y, v4.z, v4.w};
    float acc[4][4];
    #pragma unroll
    for (int ii = 0; ii < 4; ++ii)
        #pragma unroll
        for (int jj = 0; jj < 4; ++jj)
            acc[ii][jj] = 0.6f*(uu[ii] + vv[jj]);
    __syncthreads();
    #pragma unroll 4
    for (int cq = 0; cq < 16; ++cq){
        float4 qa = ((const float4*)att)[cq];
        qa.x *= 0.4f; qa.y *= 0.4f; qa.z *= 0.4f; qa.w *= 0.4f;
        float4 a[4], b[4];
        #pragma unroll
        for (int ii = 0; ii < 4; ++ii) a[ii] = ((float4*)&xr_s[iL+ii][0])[cq];
        #pragma unroll
        for (int jj = 0; jj < 4; ++jj) b[jj] = ((float4*)&xl_s[jL+jj][0])[cq];
        #pragma unroll
        for (int ii = 0; ii < 4; ++ii)
            #pragma unroll
            for (int jj = 0; jj < 4; ++jj){
                float e = acc[ii][jj];
                e = fmaf(qa.x, fabsf(a[ii].x + b[jj].x), e);
                e = fmaf(qa.y, fabsf(a[ii].y + b[jj].y), e);
                e = fmaf(qa.z, fabsf(a[ii].z + b[jj].z), e);
                e = fmaf(qa.w, fabsf(a[ii].w + b[jj].w), e);
                acc[ii][jj] = e;
            }
    }
    float w[4][4];
    #pragma unroll
    for (int ii = 0; ii < 4; ++ii){
        int i = i0 + iL + ii;
        float4 sa = *(const float4*)&sadj[(size_t)i*NN + j0 + jL];
        float4 dd = *(const float4*)&dyn[(size_t)i*NN + j0 + jL];
        float fu[4] = { g*sa.x + (1.f-g)*dd.x, g*sa.y + (1.f-g)*dd.y,
                        g*sa.z + (1.f-g)*dd.z, g*sa.w + (1.f-g)*dd.w };
        #pragma unroll
        for (int jj = 0; jj < 4; ++jj){
            bool m = (fu[jj] > 0.f) || (i == j0 + jL + jj);
            w[ii][jj] = m ? expf(acc[ii][jj]) : 0.f;
        }
    }
    #pragma unroll
    for (int jj = 0; jj < 4; ++jj){
        int j = j0 + jL + jj;
        float4 wv = { w[0][jj], w[1][jj], w[2][jj], w[3][jj] };
        *(float4*)&WgT[(size_t)(base+j)*NN + i0 + iL] = wv;
    }
    #pragma unroll
    for (int ii = 0; ii < 4; ++ii){
        float zi = w[ii][0] + w[ii][1] + w[ii][2] + w[ii][3];
        zi += __shfl_down(zi, 8);
        zi += __shfl_down(zi, 4);
        zi += __shfl_down(zi, 2);
        zi += __shfl_down(zi, 1);
        if (tj == 0) atomicAdd(&Z2[base + i0 + iL + ii], zi);
    }
}

// ---------------- K3b: h2 = elu((W@xl2)/Z + b); fused node-mean -> hseq --------
// tile 16i x 64c, grid (NN/16, B*T) = (32,16). thread = 1i x 4c.
__global__ __launch_bounds__(256) void k_a2(
    const float* __restrict__ WgT, const float* __restrict__ xl2,
    const float* __restrict__ Z2, const float* __restrict__ bias,
    float* __restrict__ hseq)
{
    __shared__ float a_s[64][20];
    __shared__ float x_s[64][68];
    __shared__ float msum[64];
    int bt = blockIdx.y;
    int i0 = blockIdx.x * 16;
    int base = bt * NN;
    int tid = threadIdx.x;
    int tg = tid >> 4, tc = tid & 15;
    if (tid < 64) msum[tid] = 0.f;
    float4 acc = {0,0,0,0};
    for (int jc = 0; jc < 8; ++jc){
        int j0 = jc*64;
        {   // stage WgT chunk: 64 rows x 16 floats = 256 f4
            int row = tid >> 2, c4 = tid & 3;
            ((float4*)&a_s[row][0])[c4] = ((const float4*)&WgT[(size_t)(base+j0+row)*NN + i0])[c4];
        }
        #pragma unroll
        for (int q = 0; q < 4; ++q){ // stage xl chunk: 64 rows x 64 = 1024 f4
            int idx = q*256 + tid; int row = idx >> 4, c4 = idx & 15;
            ((float4*)&x_s[row][0])[c4] = ((const float4*)&xl2[(size_t)(base+j0+row)*HH])[c4];
        }
        __syncthreads();
        #pragma unroll 8
        for (int j = 0; j < 64; ++j){
            float a = a_s[j][tg];
            float4 xv = ((float4*)&x_s[j][0])[tc];
            acc.x = fmaf(a, xv.x, acc.x);
            acc.y = fmaf(a, xv.y, acc.y);
            acc.z = fmaf(a, xv.z, acc.z);
            acc.w = fmaf(a, xv.w, acc.w);
        }
        __syncthreads();
    }
    float rz = 1.f / Z2[base + i0 + tg];
    float4 b4 = ((const float4*)bias)[tc];
    float4 h;
    h.x = elu1(acc.x*rz + b4.x);
    h.y = elu1(acc.y*rz + b4.y);
    h.z = elu1(acc.z*rz + b4.z);
    h.w = elu1(acc.w*rz + b4.w);
    atomicAdd(&msum[tc*4+0], h.x);
    atomicAdd(&msum[tc*4+1], h.y);
    atomicAdd(&msum[tc*4+2], h.z);
    atomicAdd(&msum[tc*4+3], h.w);
    __syncthreads();
    if (tid < 64) atomicAdd(&hseq[bt*HH + tid], msum[tid]*(1.f/(float)NN));
}

// ---------------- K4: fused GRU x2 + head --------------------------------------
__global__ __launch_bounds__(384) void k_gruhead(
    const float* __restrict__ hseq,
    const float* __restrict__ Wih0, const float* __restrict__ Whh0,
    const float* __restrict__ bih0, const float* __restrict__ bhh0,
    const float* __restrict__ Wih1, const float* __restrict__ Whh1,
    const float* __restrict__ bih1, const float* __restrict__ bhh1,
    const float* __restrict__ lamp, const float* __restrict__ attn_W,
    const float* __restrict__ attn_b, const float* __restrict__ W1,
    const float* __restrict__ b1, const float* __restrict__ ln_g,
    const float* __restrict__ ln_b, const float* __restrict__ W2,
    const float* __restrict__ b2, float* __restrict__ out)
{
    __shared__ float W_s[64*192];        // 48KB, reused (Wih then Whh per layer)
    __shared__ float gi_s[BB*TT*192];    // 12.3KB
    __shared__ float x_s[BB*TT*HH];
    __shared__ float y_s[BB*TT*HH];
    __shared__ float h_s[BB][HH];
    __shared__ float gh_s[BB][192];
    __shared__ float sc_s[BB][TT], at_s[BB][TT];
    __shared__ float fin_s[BB][HH], z_s[BB][HH], g_s[BB][HH];
    __shared__ float mu_s[BB], iv_s[BB];
    int tid = threadIdx.x;
    int b = tid / 192, g = tid % 192;
    for (int k = tid; k < BB*TT*HH; k += 384) x_s[k] = hseq[k];
    for (int L = 0; L < 2; ++L){
        const float* Wih = L ? Wih1 : Wih0;
        const float* Whh = L ? Whh1 : Whh0;
        const float* bih = L ? bih1 : bih0;
        const float* bhh = L ? bhh1 : bhh0;
        __syncthreads();
        for (int k = tid; k < 64*192; k += 384) W_s[k] = Wih[k];
        __syncthreads();
        {
            float accT[TT];
            #pragma unroll
            for (int t = 0; t < TT; ++t) accT[t] = bih[g];
            for (int k = 0; k < HH; ++k){
                float wk = W_s[k*192 + g];
                #pragma unroll
                for (int t = 0; t < TT; ++t)
                    accT[t] = fmaf(x_s[(b*TT+t)*HH + k], wk, accT[t]);
            }
            #pragma unroll
            for (int t = 0; t < TT; ++t) gi_s[(b*TT+t)*192 + g] = accT[t];
        }
        __syncthreads();
        for (int k = tid; k < 64*192; k += 384) W_s[k] = Whh[k];
        if (tid < BB*HH) h_s[tid>>6][tid&63] = 0.f;
        __syncthreads();
        for (int t = 0; t < TT; ++t){
            float gh = bhh[g];
            #pragma unroll 8
            for (int k = 0; k < HH; ++k)
                gh = fmaf(h_s[b][k], W_s[k*192 + g], gh);
            gh_s[b][g] = gh;
            __syncthreads();
            if (tid < BB*HH){
                int b2 = tid >> 6, gg = tid & 63;
                const float* gi = &gi_s[(b2*TT+t)*192];
                float r = sigm(gi[gg]      + gh_s[b2][gg]);
                float z = sigm(gi[64+gg]   + gh_s[b2][64+gg]);
                float n = tanhf(gi[128+gg] + r*gh_s[b2][128+gg]);
                float hn = (1.f - z)*n + z*h_s[b2][gg];
                h_s[b2][gg] = hn;
                y_s[(b2*TT + t)*HH + gg] = hn;
            }
            __syncthreads();
        }
        if (L == 0){
            for (int k = tid; k < BB*TT*HH; k += 384) x_s[k] = y_s[k];
        }
    }
    __syncthreads();
    // ---- head (y_s == gru2) ----
    float lam = fmaxf(lamp[0], 0.01f);
    if (tid < TT) out[BB*NC + tid] = expf(-lam*(float)tid);
    if (tid < BB*TT){
        int bb = tid >> 3, t = tid & 7;
        float s = attn_b[0];
        const float* r = &y_s[(bb*TT+t)*HH];
        for (int h = 0; h < HH; ++h) s += r[h]*attn_W[h];
        sc_s[bb][t] = s;
    }
    __syncthreads();
    if (tid < BB){
        float mx = -INFINITY;
        for (int t = 0; t < TT; ++t) mx = fmaxf(mx, sc_s[tid][t]);
        float se = 0.f;
        for (int t = 0; t < TT; ++t){ float w = expf(sc_s[tid][t]-mx); at_s[tid][t] = w; se += w; }
        for (int t = 0; t < TT; ++t){
            at_s[tid][t] /= se;
            out[BB*NC + TT + tid*TT + t] = at_s[tid][t];
        }
    }
    __syncthreads();
    if (tid < BB*HH){
        int bb = tid >> 6, h = tid & 63;
        float a = 0.f;
        for (int t = 0; t < TT; ++t) a += at_s[bb][t]*y_s[(bb*TT+t)*HH + h];
        fin_s[bb][h] = a;
    }
    __syncthreads();
    if (tid < BB*HH){
        int bb = tid >> 6, h = tid & 63;
        float a = b1[h];
        for (int k = 0; k < HH; ++k) a += fin_s[bb][k]*W1[k*HH+h];
        z_s[bb][h] = a;
    }
    __syncthreads();
    if (tid < BB){
        float mu = 0.f;
        for (int h = 0; h < HH; ++h) mu += z_s[tid][h];
        mu *= (1.f/HH);
        float v = 0.f;
        for (int h = 0; h < HH; ++h){ float d = z_s[tid][h]-mu; v += d*d; }
        v *= (1.f/HH);
        mu_s[tid] = mu; iv_s[tid] = 1.f/sqrtf(v + 1e-5f);
    }
    __syncthreads();
    if (tid < BB*HH){
        int bb = tid >> 6, h = tid & 63;
        float zn = (z_s[bb][h]-mu_s[bb])*iv_s[bb]*ln_g[h] + ln_b[h];
        g_s[bb][h] = 0.5f*zn*(1.f + erff(zn*0.70710678118654752f));
    }
    __syncthreads();
    if (tid < BB*NC){
        int bb = tid / NC, c = tid % NC;
        float a = b2[c];
        for (int k = 0; k < HH; ++k) a += g_s[bb][k]*W2[k*NC+c];
        out[bb*NC + c] = a;
    }
}

extern "C" void kernel_launch(void* const* d_in, const int* in_sizes, int n_in,
                              void* d_out, int out_size, void* d_ws, size_t ws_size,
                              hipStream_t stream)
{
    const float* x_seq = (const float*)d_in[0];
    const float* sadj  = (const float*)d_in[1];
    const float* dynW  = (const float*)d_in[2];
    const float* lamp  = (const float*)d_in[3];
    const float* g1_Wl = (const float*)d_in[4];
    const float* g1_Wr = (const float*)d_in[5];
    const float* g1_att= (const float*)d_in[6];
    const float* g1_b  = (const float*)d_in[7];
    const float* g2_Wl = (const float*)d_in[8];
    const float* g2_Wr = (const float*)d_in[9];
    const float* g2_att= (const float*)d_in[10];
    const float* g2_b  = (const float*)d_in[11];
    const float* Wih0  = (const float*)d_in[12];
    const float* Whh0  = (const float*)d_in[13];
    const float* bih0  = (const float*)d_in[14];
    const float* bhh0  = (const float*)d_in[15];
    const float* Wih1  = (const float*)d_in[16];
    const float* Whh1  = (const float*)d_in[17];
    const float* bih1  = (const float*)d_in[18];
    const float* bhh1  = (const float*)d_in[19];
    const float* attnW = (const float*)d_in[20];
    const float* attnb = (const float*)d_in[21];
    const float* W1    = (const float*)d_in[22];
    const float* b1    = (const float*)d_in[23];
    const float* lng   = (const float*)d_in[24];
    const float* lnb   = (const float*)d_in[25];
    const float* W2    = (const float*)d_in[26];
    const float* b2    = (const float*)d_in[27];
    float* out = (float*)d_out;
    float* ws  = (float*)d_ws;

    const int RWS = BB*TT*NN*HH;           // 524288
    float* dyn  = ws;                      // 262144
    float* Z2   = dyn  + NN*NN;            // 8192
    float* AB   = Z2   + BB*TT*NN;         // 16
    float* ui   = AB   + 16;               // 8192
    float* vj   = ui   + BB*TT*NN;         // 8192
    float* h1   = vj   + BB*TT*NN;         // 524288
    float* xl2  = h1   + RWS;              // 524288
    float* xr2  = xl2  + RWS;              // 524288
    float* WgT  = xr2  + RWS;              // 4194304
    float* hseq = WgT  + (size_t)BB*TT*NN*NN; // 1024
    // total ~22.1 MB

    k_dyn <<<NN*NN/256, 256, 0, stream>>>(dynW, dyn, Z2, hseq, g1_att, g1_Wr, g1_Wl, AB);
    k_gat1<<<dim3(NN/4, BB*TT), 256, 0, stream>>>(x_seq, sadj, dyn, lamp, g1_Wl, g1_Wr, g1_att, g1_b, AB, h1);
    k_lin2<<<BB*TT*NN/32, 256, 0, stream>>>(h1, g2_Wl, g2_Wr, g2_att, xl2, xr2, ui, vj);
    k_e2  <<<dim3(NN/64, NN/64, BB*TT), 256, 0, stream>>>(xl2, xr2, sadj, dyn, lamp, g2_att, ui, vj, WgT, Z2);
    k_a2  <<<dim3(NN/16, BB*TT), 256, 0, stream>>>(WgT, xl2, Z2, g2_b, hseq);
    k_gruhead<<<1, 384, 0, stream>>>(hseq, Wih0, Whh0, bih0, bhh0, Wih1, Whh1, bih1, bhh1,
                                     lamp, attnW, attnb, W1, b1, lng, lnb, W2, b2, out);
}

// Round 4
// 226.086 us; speedup vs baseline: 1.4679x; 1.0086x over previous
//
#include <hip/hip_runtime.h>
#include <math.h>

#define BB 2
#define TT 8
#define NN 512
#define HH 64
#define NC 10

typedef unsigned char uchar;

__device__ __forceinline__ float elu1(float v){ return v > 0.f ? v : expm1f(v); }
__device__ __forceinline__ float sigm(float v){ return 1.f/(1.f+expf(-v)); }

// ---------------- K0: build masks M0/M1; zero Z2/hseq; compute AB --------------
// M0[i][j] = sadj>0 || i==j ;  M1[i][j] = M0 || (dW[i][j]+dW[j][i] > 0)
// grid (8,8), block 256; 64x64 tile; transpose via LDS (pitch 65, conflict-free)
__global__ __launch_bounds__(256) void k_mask(
    const float* __restrict__ dW, const float* __restrict__ sadj,
    uchar* __restrict__ M0, uchar* __restrict__ M1,
    float* __restrict__ Z2, float* __restrict__ hseq,
    const float* __restrict__ att1, const float* __restrict__ Wr1,
    const float* __restrict__ Wl1, float* __restrict__ AB)
{
    __shared__ float tr[64][65];
    int bx = blockIdx.x, by = blockIdx.y;
    int i0 = by*64, j0 = bx*64;
    int tid = threadIdx.x;
    // stage dW^T tile: tr[r][c] = dW[(j0+r)][i0+c]
    #pragma unroll
    for (int q = 0; q < 4; ++q){
        int r = (tid >> 4) + 16*q, c4 = tid & 15;
        float4 v = *(const float4*)&dW[(size_t)(j0+r)*NN + i0 + 4*c4];
        tr[r][4*c4+0] = v.x; tr[r][4*c4+1] = v.y;
        tr[r][4*c4+2] = v.z; tr[r][4*c4+3] = v.w;
    }
    __syncthreads();
    #pragma unroll
    for (int q = 0; q < 4; ++q){
        int row = (tid >> 4) + 16*q, c4 = tid & 15;
        int i = i0 + row, j = j0 + 4*c4;
        float4 d  = *(const float4*)&dW[(size_t)i*NN + j];
        float4 sa = *(const float4*)&sadj[(size_t)i*NN + j];
        uchar4 m0, m1;
        float dd0 = d.x + tr[4*c4+0][row];
        float dd1 = d.y + tr[4*c4+1][row];
        float dd2 = d.z + tr[4*c4+2][row];
        float dd3 = d.w + tr[4*c4+3][row];
        m0.x = (sa.x > 0.f) || (i == j+0);
        m0.y = (sa.y > 0.f) || (i == j+1);
        m0.z = (sa.z > 0.f) || (i == j+2);
        m0.w = (sa.w > 0.f) || (i == j+3);
        m1.x = m0.x || (dd0 > 0.f);
        m1.y = m0.y || (dd1 > 0.f);
        m1.z = m0.z || (dd2 > 0.f);
        m1.w = m0.w || (dd3 > 0.f);
        *(uchar4*)&M0[(size_t)i*NN + j] = m0;
        *(uchar4*)&M1[(size_t)i*NN + j] = m1;
    }
    int flat = (by*8 + bx)*256 + tid;
    if (flat < BB*TT*NN) Z2[flat] = 0.f;
    else if (flat < BB*TT*NN + BB*TT*HH) hseq[flat - BB*TT*NN] = 0.f;
    if (bx == 0 && by == 0 && tid < 8){
        int h = tid & 3;
        const float* W = (tid < 4) ? Wr1 : Wl1;
        float s = 0.f;
        for (int c = 0; c < 16; ++c) s += att1[h*16+c]*W[h*16+c];
        AB[tid] = s;   // [0..4)=Ar_h, [4..8)=Al_h
    }
}

// ---------------- K1: GAT1 fused with lin2 (h1 stays in LDS) -------------------
// e^h = 0.6(xi*Ar_h + xj*Al_h) + sum_c 0.4*att_c*|xi*Wr_c + xj*Wl_c|
// block: 4 i-rows x 64 j-lanes (8 j each). grid: (NN/4, B*T)
__global__ __launch_bounds__(256) void k_gat1f(
    const float* __restrict__ x_seq, const uchar* __restrict__ M0,
    const uchar* __restrict__ M1,
    const float* __restrict__ Wl, const float* __restrict__ Wr,
    const float* __restrict__ att, const float* __restrict__ bias,
    const float* __restrict__ AB,
    const float* __restrict__ Wl2, const float* __restrict__ Wr2,
    const float* __restrict__ att2,
    float* __restrict__ xl2, float* __restrict__ xr2,
    float* __restrict__ ui, float* __restrict__ vj)
{
    __shared__ float x_s[NN];
    __shared__ float S_s[4][4];
    __shared__ float h_s[4][HH];
    __shared__ float Wl2_s[64*64];
    __shared__ float Wr2_s[64*64];
    int bt = blockIdx.y; int t = bt % TT;
    int i0 = blockIdx.x * 4;
    int tid = threadIdx.x;
    int il = tid >> 6, jl = tid & 63;
    int i = i0 + il;
    const uchar* M = t ? M1 : M0;
    ((float2*)x_s)[tid] = ((const float2*)(x_seq + bt*NN))[tid];
    #pragma unroll
    for (int q = 0; q < 4; ++q){
        int idx = q*256 + tid;
        ((float4*)Wl2_s)[idx] = ((const float4*)Wl2)[idx];
        ((float4*)Wr2_s)[idx] = ((const float4*)Wr2)[idx];
    }
    __syncthreads();
    float xi = x_s[i];
    const uchar* Mrow = M + (size_t)i*NN;
    float xj[8], msk[8];
    #pragma unroll
    for (int jj = 0; jj < 8; ++jj){
        int j = jj*64 + jl;
        xj[jj] = x_s[j];
        msk[jj] = Mrow[j] ? 1.f : 0.f;
    }
    float sw[4] = {0,0,0,0}, swx[4] = {0,0,0,0};
    for (int h = 0; h < 4; ++h){
        float acc[8] = {0,0,0,0,0,0,0,0};
        #pragma unroll
        for (int c = 0; c < 16; ++c){
            int hc = h*16 + c;
            float wl = Wl[hc];
            float q  = 0.4f * att[hc];
            float pr = xi * Wr[hc];
            #pragma unroll
            for (int jj = 0; jj < 8; ++jj){
                float s = fmaf(xj[jj], wl, pr);
                acc[jj] = fmaf(q, fabsf(s), acc[jj]);
            }
        }
        float lin = 0.6f * xi * AB[h];
        float al6 = 0.6f * AB[4+h];
        #pragma unroll
        for (int jj = 0; jj < 8; ++jj){
            float e = acc[jj] + fmaf(al6, xj[jj], lin);
            float w = msk[jj] * __expf(e);
            sw[h] += w;
            swx[h] = fmaf(w, xj[jj], swx[h]);
        }
    }
    #pragma unroll
    for (int off = 32; off; off >>= 1){
        #pragma unroll
        for (int h = 0; h < 4; ++h){
            sw[h]  += __shfl_down(sw[h],  off);
            swx[h] += __shfl_down(swx[h], off);
        }
    }
    if (jl == 0){
        #pragma unroll
        for (int h = 0; h < 4; ++h) S_s[il][h] = swx[h] / sw[h];
    }
    __syncthreads();
    {   // h1 rows in LDS
        int hc = tid & 63, row = tid >> 6;
        float v = S_s[row][hc >> 4] * Wl[hc] + bias[hc];
        h_s[row][hc] = elu1(v);
    }
    __syncthreads();
    {   // fused lin2: xl2/xr2 = h_s @ {Wl2, Wr2}; ui/vj att-dots
        int c = tid & 63, row = tid >> 6;
        float al = 0.f, ar = 0.f;
        #pragma unroll 8
        for (int k = 0; k < 64; ++k){
            float hv = h_s[row][k];
            al = fmaf(hv, Wl2_s[k*64 + c], al);
            ar = fmaf(hv, Wr2_s[k*64 + c], ar);
        }
        size_t ridx = (size_t)(bt*NN + i0 + row);
        xl2[ridx*HH + c] = al;
        xr2[ridx*HH + c] = ar;
        float a2 = att2[c];
        float pu = a2 * ar, pv = a2 * al;
        #pragma unroll
        for (int off = 32; off; off >>= 1){
            pu += __shfl_down(pu, off);
            pv += __shfl_down(pv, off);
        }
        if (c == 0){ ui[ridx] = pu; vj[ridx] = pv; }
    }
}

// ---------------- K2: GAT2 scores -> WgT[j][i] = exp(e) masked, Z atomics ------
// block tile 64i x 64j, thread = 4i x 4j. grid (8, 8, 16).
// LDS tiles stored TRANSPOSED [c][node] -> all reads conflict-free.
__global__ __launch_bounds__(256) void k_e2(
    const float* __restrict__ xl2, const float* __restrict__ xr2,
    const uchar* __restrict__ M0, const uchar* __restrict__ M1,
    const float* __restrict__ att,
    const float* __restrict__ ui, const float* __restrict__ vj,
    float* __restrict__ WgT, float* __restrict__ Z2)
{
    __shared__ float xrT[64][68];   // [c][i-rel]
    __shared__ float xlT[64][68];   // [c][j-rel]
    int bt = blockIdx.z, t = bt % TT;
    int i0 = blockIdx.y*64, j0 = blockIdx.x*64;
    int base = bt*NN;
    int tid = threadIdx.x;
    const uchar* M = t ? M1 : M0;
    {
        int r = tid >> 2;
        #pragma unroll
        for (int q = 0; q < 4; ++q){
            int c4 = (tid & 3) + 4*q;
            float4 a = *(const float4*)&xr2[(size_t)(base+i0+r)*HH + 4*c4];
            float4 b = *(const float4*)&xl2[(size_t)(base+j0+r)*HH + 4*c4];
            xrT[4*c4+0][r] = a.x; xrT[4*c4+1][r] = a.y;
            xrT[4*c4+2][r] = a.z; xrT[4*c4+3][r] = a.w;
            xlT[4*c4+0][r] = b.x; xlT[4*c4+1][r] = b.y;
            xlT[4*c4+2][r] = b.z; xlT[4*c4+3][r] = b.w;
        }
    }
    int ti = tid >> 4, tj = tid & 15;
    int iL = ti*4, jL = tj*4;
    float4 u4 = *(const float4*)&ui[base+i0+iL];
    float4 v4 = *(const float4*)&vj[base+j0+jL];
    float uu[4] = {u4.x, u4.y, u4.z, u4.w};
    float vv[4] = {v4.x, v4.y, v4.z, v4.w};
    float acc[4][4];
    #pragma unroll
    for (int ii = 0; ii < 4; ++ii)
        #pragma unroll
        for (int jj = 0; jj < 4; ++jj)
            acc[ii][jj] = 0.6f*(uu[ii] + vv[jj]);
    __syncthreads();
    #pragma unroll 8
    for (int c = 0; c < 64; ++c){
        float qa = 0.4f * att[c];                 // uniform -> s_load
        float4 a4 = *(const float4*)&xrT[c][iL];  // b128, broadcast x16
        float4 b4 = *(const float4*)&xlT[c][jL];  // b128, 2-way free
        float a[4] = {a4.x, a4.y, a4.z, a4.w};
        float b[4] = {b4.x, b4.y, b4.z, b4.w};
        #pragma unroll
        for (int ii = 0; ii < 4; ++ii)
            #pragma unroll
            for (int jj = 0; jj < 4; ++jj)
                acc[ii][jj] = fmaf(qa, fabsf(a[ii] + b[jj]), acc[ii][jj]);
    }
    float w[4][4];
    #pragma unroll
    for (int ii = 0; ii < 4; ++ii){
        int i = i0 + iL + ii;
        uchar4 mr = *(const uchar4*)&M[(size_t)i*NN + j0 + jL];
        w[ii][0] = mr.x ? __expf(acc[ii][0]) : 0.f;
        w[ii][1] = mr.y ? __expf(acc[ii][1]) : 0.f;
        w[ii][2] = mr.z ? __expf(acc[ii][2]) : 0.f;
        w[ii][3] = mr.w ? __expf(acc[ii][3]) : 0.f;
    }
    #pragma unroll
    for (int jj = 0; jj < 4; ++jj){
        int j = j0 + jL + jj;
        float4 wv = { w[0][jj], w[1][jj], w[2][jj], w[3][jj] };
        *(float4*)&WgT[(size_t)(base+j)*NN + i0 + iL] = wv;
    }
    #pragma unroll
    for (int ii = 0; ii < 4; ++ii){
        float zi = w[ii][0] + w[ii][1] + w[ii][2] + w[ii][3];
        zi += __shfl_down(zi, 8);
        zi += __shfl_down(zi, 4);
        zi += __shfl_down(zi, 2);
        zi += __shfl_down(zi, 1);
        if (tj == 0) atomicAdd(&Z2[base + i0 + iL + ii], zi);
    }
}

// ---------------- K3: h2 = elu((W@xl2)/Z + b); fused node-mean -> hseq ---------
// tile 16i x 64c, grid (NN/16, B*T). thread = 1i x 4c.
__global__ __launch_bounds__(256) void k_a2(
    const float* __restrict__ WgT, const float* __restrict__ xl2,
    const float* __restrict__ Z2, const float* __restrict__ bias,
    float* __restrict__ hseq)
{
    __shared__ float a_s[64][20];
    __shared__ float x_s[64][68];
    __shared__ float msum[64];
    int bt = blockIdx.y;
    int i0 = blockIdx.x * 16;
    int base = bt * NN;
    int tid = threadIdx.x;
    int tg = tid >> 4, tc = tid & 15;
    if (tid < 64) msum[tid] = 0.f;
    float4 acc = {0,0,0,0};
    for (int jc = 0; jc < 8; ++jc){
        int j0 = jc*64;
        {
            int row = tid >> 2, c4 = tid & 3;
            ((float4*)&a_s[row][0])[c4] = ((const float4*)&WgT[(size_t)(base+j0+row)*NN + i0])[c4];
        }
        #pragma unroll
        for (int q = 0; q < 4; ++q){
            int idx = q*256 + tid; int row = idx >> 4, c4 = idx & 15;
            ((float4*)&x_s[row][0])[c4] = ((const float4*)&xl2[(size_t)(base+j0+row)*HH])[c4];
        }
        __syncthreads();
        #pragma unroll 8
        for (int j = 0; j < 64; ++j){
            float a = a_s[j][tg];
            float4 xv = ((float4*)&x_s[j][0])[tc];
            acc.x = fmaf(a, xv.x, acc.x);
            acc.y = fmaf(a, xv.y, acc.y);
            acc.z = fmaf(a, xv.z, acc.z);
            acc.w = fmaf(a, xv.w, acc.w);
        }
        __syncthreads();
    }
    float rz = 1.f / Z2[base + i0 + tg];
    float4 b4 = ((const float4*)bias)[tc];
    float4 h;
    h.x = elu1(acc.x*rz + b4.x);
    h.y = elu1(acc.y*rz + b4.y);
    h.z = elu1(acc.z*rz + b4.z);
    h.w = elu1(acc.w*rz + b4.w);
    atomicAdd(&msum[tc*4+0], h.x);
    atomicAdd(&msum[tc*4+1], h.y);
    atomicAdd(&msum[tc*4+2], h.z);
    atomicAdd(&msum[tc*4+3], h.w);
    __syncthreads();
    if (tid < 64) atomicAdd(&hseq[bt*HH + tid], msum[tid]*(1.f/(float)NN));
}

// ---------------- K4: fused GRU x2 + head --------------------------------------
__global__ __launch_bounds__(512) void k_gruhead(
    const float* __restrict__ hseq,
    const float* __restrict__ Wih0, const float* __restrict__ Whh0,
    const float* __restrict__ bih0, const float* __restrict__ bhh0,
    const float* __restrict__ Wih1, const float* __restrict__ Whh1,
    const float* __restrict__ bih1, const float* __restrict__ bhh1,
    const float* __restrict__ lamp, const float* __restrict__ attn_W,
    const float* __restrict__ attn_b, const float* __restrict__ W1,
    const float* __restrict__ b1, const float* __restrict__ ln_g,
    const float* __restrict__ ln_b, const float* __restrict__ W2,
    const float* __restrict__ b2, float* __restrict__ out)
{
    __shared__ float W_s[64*192];
    __shared__ float gi_s[BB*TT*192];
    __shared__ float x_s[BB*TT*HH];
    __shared__ float y_s[BB*TT*HH];
    __shared__ float h_s[BB][HH];
    __shared__ float gh_s[BB][192];
    __shared__ float sc_s[BB][TT], at_s[BB][TT];
    __shared__ float fin_s[BB][HH], z_s[BB][HH], g_s[BB][HH];
    __shared__ float mu_s[BB], iv_s[BB];
    int tid = threadIdx.x;
    int b = tid / 192, g = tid % 192;
    for (int k = tid; k < BB*TT*HH; k += 512) x_s[k] = hseq[k];
    for (int L = 0; L < 2; ++L){
        const float* Wih = L ? Wih1 : Wih0;
        const float* Whh = L ? Whh1 : Whh0;
        const float* bih = L ? bih1 : bih0;
        const float* bhh = L ? bhh1 : bhh0;
        __syncthreads();
        for (int k = tid; k < 64*192; k += 512) W_s[k] = Wih[k];
        __syncthreads();
        if (tid < 384){
            float accT[TT];
            #pragma unroll
            for (int t = 0; t < TT; ++t) accT[t] = bih[g];
            for (int k = 0; k < HH; ++k){
                float wk = W_s[k*192 + g];
                #pragma unroll
                for (int t = 0; t < TT; ++t)
                    accT[t] = fmaf(x_s[(b*TT+t)*HH + k], wk, accT[t]);
            }
            #pragma unroll
            for (int t = 0; t < TT; ++t) gi_s[(b*TT+t)*192 + g] = accT[t];
        }
        __syncthreads();
        for (int k = tid; k < 64*192; k += 512) W_s[k] = Whh[k];
        if (tid < BB*HH) h_s[tid>>6][tid&63] = 0.f;
        __syncthreads();
        for (int t = 0; t < TT; ++t){
            if (tid < 384){
                float gh = bhh[g];
                #pragma unroll 8
                for (int k = 0; k < HH; ++k)
                    gh = fmaf(h_s[b][k], W_s[k*192 + g], gh);
                gh_s[b][g] = gh;
            }
            __syncthreads();
            if (tid < BB*HH){
                int b2 = tid >> 6, gg = tid & 63;
                const float* gi = &gi_s[(b2*TT+t)*192];
                float r = sigm(gi[gg]      + gh_s[b2][gg]);
                float z = sigm(gi[64+gg]   + gh_s[b2][64+gg]);
                float n = tanhf(gi[128+gg] + r*gh_s[b2][128+gg]);
                float hn = (1.f - z)*n + z*h_s[b2][gg];
                h_s[b2][gg] = hn;
                y_s[(b2*TT + t)*HH + gg] = hn;
            }
            __syncthreads();
        }
        if (L == 0){
            for (int k = tid; k < BB*TT*HH; k += 512) x_s[k] = y_s[k];
        }
    }
    __syncthreads();
    float lam = fmaxf(lamp[0], 0.01f);
    if (tid < TT) out[BB*NC + tid] = expf(-lam*(float)tid);
    if (tid < BB*TT){
        int bb = tid >> 3, t = tid & 7;
        float s = attn_b[0];
        const float* r = &y_s[(bb*TT+t)*HH];
        for (int h = 0; h < HH; ++h) s += r[h]*attn_W[h];
        sc_s[bb][t] = s;
    }
    __syncthreads();
    if (tid < BB){
        float mx = -INFINITY;
        for (int t = 0; t < TT; ++t) mx = fmaxf(mx, sc_s[tid][t]);
        float se = 0.f;
        for (int t = 0; t < TT; ++t){ float w = expf(sc_s[tid][t]-mx); at_s[tid][t] = w; se += w; }
        for (int t = 0; t < TT; ++t){
            at_s[tid][t] /= se;
            out[BB*NC + TT + tid*TT + t] = at_s[tid][t];
        }
    }
    __syncthreads();
    if (tid < BB*HH){
        int bb = tid >> 6, h = tid & 63;
        float a = 0.f;
        for (int t = 0; t < TT; ++t) a += at_s[bb][t]*y_s[(bb*TT+t)*HH + h];
        fin_s[bb][h] = a;
    }
    __syncthreads();
    if (tid < BB*HH){
        int bb = tid >> 6, h = tid & 63;
        float a = b1[h];
        for (int k = 0; k < HH; ++k) a += fin_s[bb][k]*W1[k*HH+h];
        z_s[bb][h] = a;
    }
    __syncthreads();
    if (tid < BB){
        float mu = 0.f;
        for (int h = 0; h < HH; ++h) mu += z_s[tid][h];
        mu *= (1.f/HH);
        float v = 0.f;
        for (int h = 0; h < HH; ++h){ float d = z_s[tid][h]-mu; v += d*d; }
        v *= (1.f/HH);
        mu_s[tid] = mu; iv_s[tid] = 1.f/sqrtf(v + 1e-5f);
    }
    __syncthreads();
    if (tid < BB*HH){
        int bb = tid >> 6, h = tid & 63;
        float zn = (z_s[bb][h]-mu_s[bb])*iv_s[bb]*ln_g[h] + ln_b[h];
        g_s[bb][h] = 0.5f*zn*(1.f + erff(zn*0.70710678118654752f));
    }
    __syncthreads();
    if (tid < BB*NC){
        int bb = tid / NC, c = tid % NC;
        float a = b2[c];
        for (int k = 0; k < HH; ++k) a += g_s[bb][k]*W2[k*NC+c];
        out[bb*NC + c] = a;
    }
}

extern "C" void kernel_launch(void* const* d_in, const int* in_sizes, int n_in,
                              void* d_out, int out_size, void* d_ws, size_t ws_size,
                              hipStream_t stream)
{
    const float* x_seq = (const float*)d_in[0];
    const float* sadj  = (const float*)d_in[1];
    const float* dynW  = (const float*)d_in[2];
    const float* lamp  = (const float*)d_in[3];
    const float* g1_Wl = (const float*)d_in[4];
    const float* g1_Wr = (const float*)d_in[5];
    const float* g1_att= (const float*)d_in[6];
    const float* g1_b  = (const float*)d_in[7];
    const float* g2_Wl = (const float*)d_in[8];
    const float* g2_Wr = (const float*)d_in[9];
    const float* g2_att= (const float*)d_in[10];
    const float* g2_b  = (const float*)d_in[11];
    const float* Wih0  = (const float*)d_in[12];
    const float* Whh0  = (const float*)d_in[13];
    const float* bih0  = (const float*)d_in[14];
    const float* bhh0  = (const float*)d_in[15];
    const float* Wih1  = (const float*)d_in[16];
    const float* Whh1  = (const float*)d_in[17];
    const float* bih1  = (const float*)d_in[18];
    const float* bhh1  = (const float*)d_in[19];
    const float* attnW = (const float*)d_in[20];
    const float* attnb = (const float*)d_in[21];
    const float* W1    = (const float*)d_in[22];
    const float* b1    = (const float*)d_in[23];
    const float* lng   = (const float*)d_in[24];
    const float* lnb   = (const float*)d_in[25];
    const float* W2    = (const float*)d_in[26];
    const float* b2    = (const float*)d_in[27];
    float* out = (float*)d_out;

    const int RWS = BB*TT*NN*HH;              // 524288
    uchar* M0 = (uchar*)d_ws;                 // 262144 B
    uchar* M1 = M0 + (size_t)NN*NN;           // 262144 B
    float* fb = (float*)(M1 + (size_t)NN*NN); // 16B-aligned
    float* Z2   = fb;                         // 8192
    float* AB   = Z2   + BB*TT*NN;            // 16
    float* ui   = AB   + 16;                  // 8192
    float* vj   = ui   + BB*TT*NN;            // 8192
    float* xl2  = vj   + BB*TT*NN;            // 524288
    float* xr2  = xl2  + RWS;                 // 524288
    float* WgT  = xr2  + RWS;                 // 4194304
    float* hseq = WgT  + (size_t)BB*TT*NN*NN; // 1024
    // total ~21.3 MB

    k_mask <<<dim3(8,8), 256, 0, stream>>>(dynW, sadj, M0, M1, Z2, hseq, g1_att, g1_Wr, g1_Wl, AB);
    k_gat1f<<<dim3(NN/4, BB*TT), 256, 0, stream>>>(x_seq, M0, M1, g1_Wl, g1_Wr, g1_att, g1_b, AB,
                                                   g2_Wl, g2_Wr, g2_att, xl2, xr2, ui, vj);
    k_e2   <<<dim3(NN/64, NN/64, BB*TT), 256, 0, stream>>>(xl2, xr2, M0, M1, g2_att, ui, vj, WgT, Z2);
    k_a2   <<<dim3(NN/16, BB*TT), 256, 0, stream>>>(WgT, xl2, Z2, g2_b, hseq);
    k_gruhead<<<1, 512, 0, stream>>>(hseq, Wih0, Whh0, bih0, bhh0, Wih1, Whh1, bih1, bhh1,
                                     lamp, attnW, attnb, W1, b1, lng, lnb, W2, b2, out);
}

// Round 5
// 222.985 us; speedup vs baseline: 1.4883x; 1.0139x over previous
//
#include <hip/hip_runtime.h>
#include <math.h>

#define BB 2
#define TT 8
#define NN 512
#define HH 64
#define NC 10

typedef unsigned char uchar;

__device__ __forceinline__ float elu1(float v){ return v > 0.f ? v : expm1f(v); }
__device__ __forceinline__ float sigm(float v){ return 1.f/(1.f+expf(-v)); }

// ---------------- K0: masks M0/M1; zero Z2/hseq; AB; weight transposes ---------
// z==0 (64 blocks): M0[i][j] = sadj>0 || i==j ; M1 = M0 || (dW+dW^T > 0)
// z==1 (64 blocks): WT4 quad-transposes of Whh0, Wih1, Whh1
__global__ __launch_bounds__(256) void k_mask(
    const float* __restrict__ dW, const float* __restrict__ sadj,
    uchar* __restrict__ M0, uchar* __restrict__ M1,
    float* __restrict__ Z2, float* __restrict__ hseq,
    const float* __restrict__ att1, const float* __restrict__ Wr1,
    const float* __restrict__ Wl1, float* __restrict__ AB,
    const float* __restrict__ Whh0, const float* __restrict__ Wih1,
    const float* __restrict__ Whh1, float4* __restrict__ WT4)
{
    __shared__ float tr[64][65];
    int bx = blockIdx.x, by = blockIdx.y;
    int tid = threadIdx.x;
    if (blockIdx.z == 1){
        // quad-transpose: WT4[m][gg*64+k] = {W[k][gg], W[k][64+gg], W[k][128+gg], 0}
        int idx = (by*8 + bx)*256 + tid;           // 0..16383, need 12288
        if (idx < 3*4096){
            int m = idx >> 12, r = idx & 4095;
            int gg = r >> 6, k = r & 63;
            const float* W = (m == 0) ? Whh0 : (m == 1) ? Wih1 : Whh1;
            float4 o;
            o.x = W[k*192 + gg];
            o.y = W[k*192 + 64 + gg];
            o.z = W[k*192 + 128 + gg];
            o.w = 0.f;
            WT4[(size_t)m*4096 + r] = o;
        }
        return;
    }
    int i0 = by*64, j0 = bx*64;
    #pragma unroll
    for (int q = 0; q < 4; ++q){
        int r = (tid >> 4) + 16*q, c4 = tid & 15;
        float4 v = *(const float4*)&dW[(size_t)(j0+r)*NN + i0 + 4*c4];
        tr[r][4*c4+0] = v.x; tr[r][4*c4+1] = v.y;
        tr[r][4*c4+2] = v.z; tr[r][4*c4+3] = v.w;
    }
    __syncthreads();
    #pragma unroll
    for (int q = 0; q < 4; ++q){
        int row = (tid >> 4) + 16*q, c4 = tid & 15;
        int i = i0 + row, j = j0 + 4*c4;
        float4 d  = *(const float4*)&dW[(size_t)i*NN + j];
        float4 sa = *(const float4*)&sadj[(size_t)i*NN + j];
        uchar4 m0, m1;
        float dd0 = d.x + tr[4*c4+0][row];
        float dd1 = d.y + tr[4*c4+1][row];
        float dd2 = d.z + tr[4*c4+2][row];
        float dd3 = d.w + tr[4*c4+3][row];
        m0.x = (sa.x > 0.f) || (i == j+0);
        m0.y = (sa.y > 0.f) || (i == j+1);
        m0.z = (sa.z > 0.f) || (i == j+2);
        m0.w = (sa.w > 0.f) || (i == j+3);
        m1.x = m0.x || (dd0 > 0.f);
        m1.y = m0.y || (dd1 > 0.f);
        m1.z = m0.z || (dd2 > 0.f);
        m1.w = m0.w || (dd3 > 0.f);
        *(uchar4*)&M0[(size_t)i*NN + j] = m0;
        *(uchar4*)&M1[(size_t)i*NN + j] = m1;
    }
    int flat = (by*8 + bx)*256 + tid;
    if (flat < BB*TT*NN) Z2[flat] = 0.f;
    else if (flat < BB*TT*NN + BB*TT*HH) hseq[flat - BB*TT*NN] = 0.f;
    if (bx == 0 && by == 0 && tid < 8){
        int h = tid & 3;
        const float* W = (tid < 4) ? Wr1 : Wl1;
        float s = 0.f;
        for (int c = 0; c < 16; ++c) s += att1[h*16+c]*W[h*16+c];
        AB[tid] = s;
    }
}

// ---------------- K1: GAT1 fused with lin2 (h1 stays in LDS) -------------------
__global__ __launch_bounds__(256) void k_gat1f(
    const float* __restrict__ x_seq, const uchar* __restrict__ M0,
    const uchar* __restrict__ M1,
    const float* __restrict__ Wl, const float* __restrict__ Wr,
    const float* __restrict__ att, const float* __restrict__ bias,
    const float* __restrict__ AB,
    const float* __restrict__ Wl2, const float* __restrict__ Wr2,
    const float* __restrict__ att2,
    float* __restrict__ xl2, float* __restrict__ xr2,
    float* __restrict__ ui, float* __restrict__ vj)
{
    __shared__ float x_s[NN];
    __shared__ float S_s[4][4];
    __shared__ float h_s[4][HH];
    __shared__ float Wl2_s[64*64];
    __shared__ float Wr2_s[64*64];
    int bt = blockIdx.y; int t = bt % TT;
    int i0 = blockIdx.x * 4;
    int tid = threadIdx.x;
    int il = tid >> 6, jl = tid & 63;
    int i = i0 + il;
    const uchar* M = t ? M1 : M0;
    ((float2*)x_s)[tid] = ((const float2*)(x_seq + bt*NN))[tid];
    #pragma unroll
    for (int q = 0; q < 4; ++q){
        int idx = q*256 + tid;
        ((float4*)Wl2_s)[idx] = ((const float4*)Wl2)[idx];
        ((float4*)Wr2_s)[idx] = ((const float4*)Wr2)[idx];
    }
    __syncthreads();
    float xi = x_s[i];
    const uchar* Mrow = M + (size_t)i*NN;
    float xj[8], msk[8];
    #pragma unroll
    for (int jj = 0; jj < 8; ++jj){
        int j = jj*64 + jl;
        xj[jj] = x_s[j];
        msk[jj] = Mrow[j] ? 1.f : 0.f;
    }
    float sw[4] = {0,0,0,0}, swx[4] = {0,0,0,0};
    for (int h = 0; h < 4; ++h){
        float acc[8] = {0,0,0,0,0,0,0,0};
        #pragma unroll
        for (int c = 0; c < 16; ++c){
            int hc = h*16 + c;
            float wl = Wl[hc];
            float q  = 0.4f * att[hc];
            float pr = xi * Wr[hc];
            #pragma unroll
            for (int jj = 0; jj < 8; ++jj){
                float s = fmaf(xj[jj], wl, pr);
                acc[jj] = fmaf(q, fabsf(s), acc[jj]);
            }
        }
        float lin = 0.6f * xi * AB[h];
        float al6 = 0.6f * AB[4+h];
        #pragma unroll
        for (int jj = 0; jj < 8; ++jj){
            float e = acc[jj] + fmaf(al6, xj[jj], lin);
            float w = msk[jj] * __expf(e);
            sw[h] += w;
            swx[h] = fmaf(w, xj[jj], swx[h]);
        }
    }
    #pragma unroll
    for (int off = 32; off; off >>= 1){
        #pragma unroll
        for (int h = 0; h < 4; ++h){
            sw[h]  += __shfl_down(sw[h],  off);
            swx[h] += __shfl_down(swx[h], off);
        }
    }
    if (jl == 0){
        #pragma unroll
        for (int h = 0; h < 4; ++h) S_s[il][h] = swx[h] / sw[h];
    }
    __syncthreads();
    {
        int hc = tid & 63, row = tid >> 6;
        float v = S_s[row][hc >> 4] * Wl[hc] + bias[hc];
        h_s[row][hc] = elu1(v);
    }
    __syncthreads();
    {
        int c = tid & 63, row = tid >> 6;
        float al = 0.f, ar = 0.f;
        #pragma unroll 8
        for (int k = 0; k < 64; ++k){
            float hv = h_s[row][k];
            al = fmaf(hv, Wl2_s[k*64 + c], al);
            ar = fmaf(hv, Wr2_s[k*64 + c], ar);
        }
        size_t ridx = (size_t)(bt*NN + i0 + row);
        xl2[ridx*HH + c] = al;
        xr2[ridx*HH + c] = ar;
        float a2 = att2[c];
        float pu = a2 * ar, pv = a2 * al;
        #pragma unroll
        for (int off = 32; off; off >>= 1){
            pu += __shfl_down(pu, off);
            pv += __shfl_down(pv, off);
        }
        if (c == 0){ ui[ridx] = pu; vj[ridx] = pv; }
    }
}

// ---------------- K2: GAT2 scores -> WgT[j][i] = exp(e) masked, Z atomics ------
__global__ __launch_bounds__(256) void k_e2(
    const float* __restrict__ xl2, const float* __restrict__ xr2,
    const uchar* __restrict__ M0, const uchar* __restrict__ M1,
    const float* __restrict__ att,
    const float* __restrict__ ui, const float* __restrict__ vj,
    float* __restrict__ WgT, float* __restrict__ Z2)
{
    __shared__ float xrT[64][68];
    __shared__ float xlT[64][68];
    int bt = blockIdx.z, t = bt % TT;
    int i0 = blockIdx.y*64, j0 = blockIdx.x*64;
    int base = bt*NN;
    int tid = threadIdx.x;
    const uchar* M = t ? M1 : M0;
    {
        int r = tid >> 2;
        #pragma unroll
        for (int q = 0; q < 4; ++q){
            int c4 = (tid & 3) + 4*q;
            float4 a = *(const float4*)&xr2[(size_t)(base+i0+r)*HH + 4*c4];
            float4 b = *(const float4*)&xl2[(size_t)(base+j0+r)*HH + 4*c4];
            xrT[4*c4+0][r] = a.x; xrT[4*c4+1][r] = a.y;
            xrT[4*c4+2][r] = a.z; xrT[4*c4+3][r] = a.w;
            xlT[4*c4+0][r] = b.x; xlT[4*c4+1][r] = b.y;
            xlT[4*c4+2][r] = b.z; xlT[4*c4+3][r] = b.w;
        }
    }
    int ti = tid >> 4, tj = tid & 15;
    int iL = ti*4, jL = tj*4;
    float4 u4 = *(const float4*)&ui[base+i0+iL];
    float4 v4 = *(const float4*)&vj[base+j0+jL];
    float uu[4] = {u4.x, u4.y, u4.z, u4.w};
    float vv[4] = {v4.x, v4.y, v4.z, v4.w};
    float acc[4][4];
    #pragma unroll
    for (int ii = 0; ii < 4; ++ii)
        #pragma unroll
        for (int jj = 0; jj < 4; ++jj)
            acc[ii][jj] = 0.6f*(uu[ii] + vv[jj]);
    __syncthreads();
    #pragma unroll 8
    for (int c = 0; c < 64; ++c){
        float qa = 0.4f * att[c];
        float4 a4 = *(const float4*)&xrT[c][iL];
        float4 b4 = *(const float4*)&xlT[c][jL];
        float a[4] = {a4.x, a4.y, a4.z, a4.w};
        float b[4] = {b4.x, b4.y, b4.z, b4.w};
        #pragma unroll
        for (int ii = 0; ii < 4; ++ii)
            #pragma unroll
            for (int jj = 0; jj < 4; ++jj)
                acc[ii][jj] = fmaf(qa, fabsf(a[ii] + b[jj]), acc[ii][jj]);
    }
    float w[4][4];
    #pragma unroll
    for (int ii = 0; ii < 4; ++ii){
        int i = i0 + iL + ii;
        uchar4 mr = *(const uchar4*)&M[(size_t)i*NN + j0 + jL];
        w[ii][0] = mr.x ? __expf(acc[ii][0]) : 0.f;
        w[ii][1] = mr.y ? __expf(acc[ii][1]) : 0.f;
        w[ii][2] = mr.z ? __expf(acc[ii][2]) : 0.f;
        w[ii][3] = mr.w ? __expf(acc[ii][3]) : 0.f;
    }
    #pragma unroll
    for (int jj = 0; jj < 4; ++jj){
        int j = j0 + jL + jj;
        float4 wv = { w[0][jj], w[1][jj], w[2][jj], w[3][jj] };
        *(float4*)&WgT[(size_t)(base+j)*NN + i0 + iL] = wv;
    }
    #pragma unroll
    for (int ii = 0; ii < 4; ++ii){
        float zi = w[ii][0] + w[ii][1] + w[ii][2] + w[ii][3];
        zi += __shfl_down(zi, 8);
        zi += __shfl_down(zi, 4);
        zi += __shfl_down(zi, 2);
        zi += __shfl_down(zi, 1);
        if (tj == 0) atomicAdd(&Z2[base + i0 + iL + ii], zi);
    }
}

// ---------------- K3: h2 = elu((W@xl2)/Z + b); fused node-mean -> hseq ---------
__global__ __launch_bounds__(256) void k_a2(
    const float* __restrict__ WgT, const float* __restrict__ xl2,
    const float* __restrict__ Z2, const float* __restrict__ bias,
    float* __restrict__ hseq)
{
    __shared__ float a_s[64][20];
    __shared__ float x_s[64][68];
    __shared__ float msum[64];
    int bt = blockIdx.y;
    int i0 = blockIdx.x * 16;
    int base = bt * NN;
    int tid = threadIdx.x;
    int tg = tid >> 4, tc = tid & 15;
    if (tid < 64) msum[tid] = 0.f;
    float4 acc = {0,0,0,0};
    for (int jc = 0; jc < 8; ++jc){
        int j0 = jc*64;
        {
            int row = tid >> 2, c4 = tid & 3;
            ((float4*)&a_s[row][0])[c4] = ((const float4*)&WgT[(size_t)(base+j0+row)*NN + i0])[c4];
        }
        #pragma unroll
        for (int q = 0; q < 4; ++q){
            int idx = q*256 + tid; int row = idx >> 4, c4 = idx & 15;
            ((float4*)&x_s[row][0])[c4] = ((const float4*)&xl2[(size_t)(base+j0+row)*HH])[c4];
        }
        __syncthreads();
        #pragma unroll 8
        for (int j = 0; j < 64; ++j){
            float a = a_s[j][tg];
            float4 xv = ((float4*)&x_s[j][0])[tc];
            acc.x = fmaf(a, xv.x, acc.x);
            acc.y = fmaf(a, xv.y, acc.y);
            acc.z = fmaf(a, xv.z, acc.z);
            acc.w = fmaf(a, xv.w, acc.w);
        }
        __syncthreads();
    }
    float rz = 1.f / Z2[base + i0 + tg];
    float4 b4 = ((const float4*)bias)[tc];
    float4 h;
    h.x = elu1(acc.x*rz + b4.x);
    h.y = elu1(acc.y*rz + b4.y);
    h.z = elu1(acc.z*rz + b4.z);
    h.w = elu1(acc.w*rz + b4.w);
    atomicAdd(&msum[tc*4+0], h.x);
    atomicAdd(&msum[tc*4+1], h.y);
    atomicAdd(&msum[tc*4+2], h.z);
    atomicAdd(&msum[tc*4+3], h.w);
    __syncthreads();
    if (tid < 64) atomicAdd(&hseq[bt*HH + tid], msum[tid]*(1.f/(float)NN));
}

// ---------------- K4: gi0 = hseq@Wih0 + bih0 (parallel) ------------------------
// grid 12 x 256: one thread per (bt, g) output
__global__ __launch_bounds__(256) void k_pre(
    const float* __restrict__ hseq, const float* __restrict__ Wih0,
    const float* __restrict__ bih0, float* __restrict__ gi0)
{
    int idx = blockIdx.x*256 + threadIdx.x;   // 0..3071
    int bt = idx / 192, g = idx % 192;
    const float* x = hseq + bt*HH;
    float acc = bih0[g];
    #pragma unroll 8
    for (int k = 0; k < HH; ++k)
        acc = fmaf(x[k], Wih0[k*192 + g], acc);
    gi0[idx] = acc;
}

// ---------------- K5: serial GRU x2 (wave-per-batch, reg-resident) + head ------
#define P4 65
__global__ __launch_bounds__(512) void k_gru2(
    const float* __restrict__ gi0, const float4* __restrict__ WT4,
    const float* __restrict__ bhh0,
    const float* __restrict__ bih1, const float* __restrict__ bhh1,
    const float* __restrict__ lamp, const float* __restrict__ attn_W,
    const float* __restrict__ attn_b, const float* __restrict__ W1,
    const float* __restrict__ b1, const float* __restrict__ ln_g,
    const float* __restrict__ ln_b, const float* __restrict__ W2,
    const float* __restrict__ b2, float* __restrict__ out)
{
    __shared__ float4 WA[64*P4];          // 66560 B  (Whh of current layer)
    __shared__ float4 WB[64*P4];          // 66560 B  (Wih1)
    __shared__ float gi_s[BB*TT*192];     // 12288 B
    __shared__ float y_s[BB*TT*HH];       // 4096 B
    __shared__ float sc_s[BB][TT], at_s[BB][TT];
    __shared__ float fin_s[BB][HH], z_s[BB][HH], g_s[BB][HH];
    __shared__ float mu_s[BB], iv_s[BB];
    int tid = threadIdx.x;
    int wave = tid >> 6, lane = tid & 63;
    // stage: WA <- Whh0T4, WB <- Wih1T4, gi_s <- gi0
    for (int v = tid; v < 4096; v += 512){
        WA[(v >> 6)*P4 + (v & 63)] = WT4[v];          // m=0: Whh0
        WB[(v >> 6)*P4 + (v & 63)] = WT4[4096 + v];   // m=1: Wih1
    }
    for (int v = tid; v < BB*TT*192; v += 512) gi_s[v] = gi0[v];
    __syncthreads();
    float y[TT];
    float g1r[TT], g1z[TT], g1n[TT];
    if (wave < 2){
        int b = wave;
        float bhr = bhh0[lane], bhz = bhh0[64+lane], bhn = bhh0[128+lane];
        float h = 0.f;
        for (int t = 0; t < TT; ++t){
            float ghr = bhr, ghz = bhz, ghn = bhn;
            #pragma unroll 16
            for (int k = 0; k < 64; ++k){
                float4 w4 = WA[lane*P4 + k];
                float hk = __shfl(h, k);
                ghr = fmaf(w4.x, hk, ghr);
                ghz = fmaf(w4.y, hk, ghz);
                ghn = fmaf(w4.z, hk, ghn);
            }
            const float* gi = &gi_s[(b*TT + t)*192];
            float r = sigm(gi[lane] + ghr);
            float z = sigm(gi[64+lane] + ghz);
            float n = tanhf(gi[128+lane] + r*ghn);
            h = (1.f - z)*n + z*h;
            y[t] = h;
        }
        // gi1 = y @ Wih1 + bih1 (in-regs, shfl-based)
        float bi1r = bih1[lane], bi1z = bih1[64+lane], bi1n = bih1[128+lane];
        #pragma unroll
        for (int t = 0; t < TT; ++t){ g1r[t] = bi1r; g1z[t] = bi1z; g1n[t] = bi1n; }
        #pragma unroll 8
        for (int k = 0; k < 64; ++k){
            float4 w4 = WB[lane*P4 + k];
            #pragma unroll
            for (int t = 0; t < TT; ++t){
                float yk = __shfl(y[t], k);
                g1r[t] = fmaf(w4.x, yk, g1r[t]);
                g1z[t] = fmaf(w4.y, yk, g1z[t]);
                g1n[t] = fmaf(w4.z, yk, g1n[t]);
            }
        }
    }
    __syncthreads();
    // waves 2..7 restage WA <- Whh1T4 (waves 0-1 skip; their gi1 is in regs)
    if (wave >= 2){
        for (int v = tid - 128; v < 4096; v += 384)
            WA[(v >> 6)*P4 + (v & 63)] = WT4[2*4096 + v];
    }
    __syncthreads();
    if (wave < 2){
        int b = wave;
        float bhr = bhh1[lane], bhz = bhh1[64+lane], bhn = bhh1[128+lane];
        float h = 0.f;
        for (int t = 0; t < TT; ++t){
            float ghr = bhr, ghz = bhz, ghn = bhn;
            #pragma unroll 16
            for (int k = 0; k < 64; ++k){
                float4 w4 = WA[lane*P4 + k];
                float hk = __shfl(h, k);
                ghr = fmaf(w4.x, hk, ghr);
                ghz = fmaf(w4.y, hk, ghz);
                ghn = fmaf(w4.z, hk, ghn);
            }
            float r = sigm(g1r[t] + ghr);
            float z = sigm(g1z[t] + ghz);
            float n = tanhf(g1n[t] + r*ghn);
            h = (1.f - z)*n + z*h;
            y_s[(b*TT + t)*HH + lane] = h;
        }
    }
    __syncthreads();
    // ---- head ----
    float lam = fmaxf(lamp[0], 0.01f);
    if (tid < TT) out[BB*NC + tid] = expf(-lam*(float)tid);
    if (tid < BB*TT){
        int bb = tid >> 3, t = tid & 7;
        float s = attn_b[0];
        const float* r = &y_s[(bb*TT+t)*HH];
        for (int h = 0; h < HH; ++h) s += r[h]*attn_W[h];
        sc_s[bb][t] = s;
    }
    __syncthreads();
    if (tid < BB){
        float mx = -INFINITY;
        for (int t = 0; t < TT; ++t) mx = fmaxf(mx, sc_s[tid][t]);
        float se = 0.f;
        for (int t = 0; t < TT; ++t){ float w = expf(sc_s[tid][t]-mx); at_s[tid][t] = w; se += w; }
        for (int t = 0; t < TT; ++t){
            at_s[tid][t] /= se;
            out[BB*NC + TT + tid*TT + t] = at_s[tid][t];
        }
    }
    __syncthreads();
    if (tid < BB*HH){
        int bb = tid >> 6, h = tid & 63;
        float a = 0.f;
        for (int t = 0; t < TT; ++t) a += at_s[bb][t]*y_s[(bb*TT+t)*HH + h];
        fin_s[bb][h] = a;
    }
    __syncthreads();
    if (tid < BB*HH){
        int bb = tid >> 6, h = tid & 63;
        float a = b1[h];
        for (int k = 0; k < HH; ++k) a += fin_s[bb][k]*W1[k*HH+h];
        z_s[bb][h] = a;
    }
    __syncthreads();
    if (tid < BB){
        float mu = 0.f;
        for (int h = 0; h < HH; ++h) mu += z_s[tid][h];
        mu *= (1.f/HH);
        float v = 0.f;
        for (int h = 0; h < HH; ++h){ float d = z_s[tid][h]-mu; v += d*d; }
        v *= (1.f/HH);
        mu_s[tid] = mu; iv_s[tid] = 1.f/sqrtf(v + 1e-5f);
    }
    __syncthreads();
    if (tid < BB*HH){
        int bb = tid >> 6, h = tid & 63;
        float zn = (z_s[bb][h]-mu_s[bb])*iv_s[bb]*ln_g[h] + ln_b[h];
        g_s[bb][h] = 0.5f*zn*(1.f + erff(zn*0.70710678118654752f));
    }
    __syncthreads();
    if (tid < BB*NC){
        int bb = tid / NC, c = tid % NC;
        float a = b2[c];
        for (int k = 0; k < HH; ++k) a += g_s[bb][k]*W2[k*NC+c];
        out[bb*NC + c] = a;
    }
}

extern "C" void kernel_launch(void* const* d_in, const int* in_sizes, int n_in,
                              void* d_out, int out_size, void* d_ws, size_t ws_size,
                              hipStream_t stream)
{
    const float* x_seq = (const float*)d_in[0];
    const float* sadj  = (const float*)d_in[1];
    const float* dynW  = (const float*)d_in[2];
    const float* lamp  = (const float*)d_in[3];
    const float* g1_Wl = (const float*)d_in[4];
    const float* g1_Wr = (const float*)d_in[5];
    const float* g1_att= (const float*)d_in[6];
    const float* g1_b  = (const float*)d_in[7];
    const float* g2_Wl = (const float*)d_in[8];
    const float* g2_Wr = (const float*)d_in[9];
    const float* g2_att= (const float*)d_in[10];
    const float* g2_b  = (const float*)d_in[11];
    const float* Wih0  = (const float*)d_in[12];
    const float* Whh0  = (const float*)d_in[13];
    const float* bih0  = (const float*)d_in[14];
    const float* bhh0  = (const float*)d_in[15];
    const float* Wih1  = (const float*)d_in[16];
    const float* Whh1  = (const float*)d_in[17];
    const float* bih1  = (const float*)d_in[18];
    const float* bhh1  = (const float*)d_in[19];
    const float* attnW = (const float*)d_in[20];
    const float* attnb = (const float*)d_in[21];
    const float* W1    = (const float*)d_in[22];
    const float* b1    = (const float*)d_in[23];
    const float* lng   = (const float*)d_in[24];
    const float* lnb   = (const float*)d_in[25];
    const float* W2    = (const float*)d_in[26];
    const float* b2    = (const float*)d_in[27];
    float* out = (float*)d_out;

    const int RWS = BB*TT*NN*HH;              // 524288
    uchar* M0 = (uchar*)d_ws;                 // 262144 B
    uchar* M1 = M0 + (size_t)NN*NN;           // 262144 B
    float* fb = (float*)(M1 + (size_t)NN*NN);
    float* Z2   = fb;                         // 8192
    float* AB   = Z2   + BB*TT*NN;            // 16
    float* ui   = AB   + 16;                  // 8192
    float* vj   = ui   + BB*TT*NN;            // 8192
    float* xl2  = vj   + BB*TT*NN;            // 524288
    float* xr2  = xl2  + RWS;                 // 524288
    float* WgT  = xr2  + RWS;                 // 4194304
    float* hseq = WgT  + (size_t)BB*TT*NN*NN; // 1024
    float* gi0  = hseq + BB*TT*HH;            // 3072
    float4* WT4 = (float4*)(gi0 + BB*TT*192); // 3*4096 float4 = 196608 B
    // total ~21.6 MB

    k_mask <<<dim3(8,8,2), 256, 0, stream>>>(dynW, sadj, M0, M1, Z2, hseq, g1_att, g1_Wr, g1_Wl, AB,
                                             Whh0, Wih1, Whh1, WT4);
    k_gat1f<<<dim3(NN/4, BB*TT), 256, 0, stream>>>(x_seq, M0, M1, g1_Wl, g1_Wr, g1_att, g1_b, AB,
                                                   g2_Wl, g2_Wr, g2_att, xl2, xr2, ui, vj);
    k_e2   <<<dim3(NN/64, NN/64, BB*TT), 256, 0, stream>>>(xl2, xr2, M0, M1, g2_att, ui, vj, WgT, Z2);
    k_a2   <<<dim3(NN/16, BB*TT), 256, 0, stream>>>(WgT, xl2, Z2, g2_b, hseq);
    k_pre  <<<12, 256, 0, stream>>>(hseq, Wih0, bih0, gi0);
    k_gru2 <<<1, 512, 0, stream>>>(gi0, WT4, bhh0, bih1, bhh1,
                                   lamp, attnW, attnb, W1, b1, lng, lnb, W2, b2, out);
}